// Round 1
// baseline (284.126 us; speedup 1.0000x reference)
//
#include <hip/hip_runtime.h>
#include <stdint.h>

#define M_DIM 4096
#define I_DIM 1024
#define O_DIM 1024
#define KB 6
#define K_DIM (I_DIM * KB)   // 6144

typedef __attribute__((ext_vector_type(8))) short short8;
typedef __attribute__((ext_vector_type(4))) float f32x4;
typedef __attribute__((ext_vector_type(4))) unsigned int u32x4;
typedef __attribute__((ext_vector_type(4))) float hfloat4;

__device__ __forceinline__ unsigned short f2bf(float f) {
  union { float f; unsigned int u; } v; v.f = f;
  unsigned int u = v.u;
  unsigned int r = (u + 0x7FFFu + ((u >> 16) & 1u)) >> 16;
  return (unsigned short)r;
}

// ---------------- Kernel 1: basis planes -> bf16 A[4096][6144], k = i*6+j ----
__global__ __launch_bounds__(256) void k_basis(const float* __restrict__ x,
                                               unsigned short* __restrict__ A) {
  int t = blockIdx.x * 256 + threadIdx.x;     // 524288 threads, 8 elements each
  long e0 = (long)t * 8;
  const hfloat4* xp = (const hfloat4*)(x + e0);
  hfloat4 v0 = xp[0], v1 = xp[1];
  float xv[8];
  xv[0]=v0[0]; xv[1]=v0[1]; xv[2]=v0[2]; xv[3]=v0[3];
  xv[4]=v1[0]; xv[5]=v1[1]; xv[6]=v1[2]; xv[7]=v1[3];
  unsigned short outv[48];
#pragma unroll
  for (int e = 0; e < 8; ++e) {
    float s  = 1.0f / (1.0f + __expf(-xv[e]));
    float b2 = s, b3 = s, b4 = s * s;
    float b5 = fmaf(s, b4, b3 + b2 + 1.0f);        // + b1(=1) + b0(=0)
    float b6 = fmaf(s, b5, b4 + b3 + b2 + 1.0f);
    float b7 = fmaf(s, b6, b5 + b4 + b3 + b2);
    float b8 = fmaf(s, b7, b6 + b5 + b4 + b3);
    outv[e*6+0] = f2bf(s);    // carries (c2+c3)
    outv[e*6+1] = f2bf(b4);   // carries c4
    outv[e*6+2] = f2bf(b5);
    outv[e*6+3] = f2bf(b6);
    outv[e*6+4] = f2bf(b7);
    outv[e*6+5] = f2bf(b8);
  }
  u32x4* dst = (u32x4*)(A + e0 * KB);          // e0*6 ushorts, 96B-aligned
  const u32x4* srcv = (const u32x4*)outv;
#pragma unroll
  for (int q = 0; q < 6; ++q) dst[q] = srcv[q];
}

// ---------------- Kernel 2: coeffs -> bf16 Bt[1024][6144] (k-contiguous) -----
__global__ __launch_bounds__(256) void k_coef(const float* __restrict__ C,
                                              unsigned short* __restrict__ Bt) {
  __shared__ unsigned short tile[32 * 192];    // [o_local][i_local*6 + j]
  int i0 = blockIdx.x * 32, o0 = blockIdx.y * 32;
  int t = threadIdx.x;
  int ol = t & 31, ig = t >> 5;                // ig: 0..7
#pragma unroll
  for (int r = 0; r < 4; ++r) {
    int il = ig + r * 8;
    const float* p = C + (size_t)(i0 + il) * (O_DIM * 9) + (size_t)(o0 + ol) * 9;
    float c2 = p[2], c3 = p[3], c4 = p[4], c5 = p[5], c6 = p[6], c7 = p[7], c8 = p[8];
    unsigned short* q = &tile[ol * 192 + il * 6];
    q[0] = f2bf(c2 + c3);
    q[1] = f2bf(c4);
    q[2] = f2bf(c5);
    q[3] = f2bf(c6);
    q[4] = f2bf(c7);
    q[5] = f2bf(c8);
  }
  __syncthreads();
  const u32x4* lsrc = (const u32x4*)tile;      // 768 chunks of 16B
#pragma unroll
  for (int r = 0; r < 3; ++r) {
    int c = t + r * 256;
    int row = c / 24, off = c % 24;            // 24 x 16B per o-row
    u32x4* gdst = (u32x4*)(Bt + (size_t)(o0 + row) * K_DIM + (size_t)i0 * 6 + off * 8);
    *gdst = lsrc[c];
  }
}

// ---------------- Kernel 2b: bias[o] = sum_i c[i][o][1] (deterministic) ------
__global__ __launch_bounds__(256) void k_bias(const float* __restrict__ C,
                                              float* __restrict__ bias) {
  int o = blockIdx.x * 256 + threadIdx.x;      // grid 4 -> 1024
  float s = 0.f;
  const float* p = C + (size_t)o * 9 + 1;
#pragma unroll 4
  for (int i = 0; i < I_DIM; ++i) s += p[(size_t)i * (O_DIM * 9)];
  bias[o] = s;
}

// ---------------- Kernel 3: bf16 GEMM, 128x128 tile, BK=64, 2-phase ----------
#define BM 128
#define BN 128
#define BKK 64
#define NKT (K_DIM / BKK)   // 96

__global__ __launch_bounds__(256) void k_gemm(const unsigned short* __restrict__ A,
                                              const unsigned short* __restrict__ Bt,
                                              const float* __restrict__ bias,
                                              float* __restrict__ out) {
  __shared__ unsigned short As[2][BM * BKK];   // 16 KB each
  __shared__ unsigned short Bs[2][BN * BKK];
  int tid = threadIdx.x;
  int wid = tid >> 6, lane = tid & 63;
  int m0 = blockIdx.y * BM, n0 = blockIdx.x * BN;
  int wm = wid >> 1, wn = wid & 1;

  auto stage = [&](int buf, int kt) {
    const char* gA = (const char*)(A + (size_t)m0 * K_DIM) + (size_t)kt * (BKK * 2);
    const char* gB = (const char*)(Bt + (size_t)n0 * K_DIM) + (size_t)kt * (BKK * 2);
    const size_t ldb = (size_t)K_DIM * 2;      // row stride in bytes
#pragma unroll
    for (int c = 0; c < 4; ++c) {
      int chunk = wid * 4 + c;                 // 0..15, 1KB each
      int r  = chunk * 8 + (lane >> 3);        // tile row
      int cb = (lane & 7) * 16;                // byte within 128B row
      unsigned short* la = &As[buf][chunk * 512];
      __builtin_amdgcn_global_load_lds(
          (const __attribute__((address_space(1))) void*)(gA + (size_t)r * ldb + cb),
          (__attribute__((address_space(3))) void*)la, 16, 0, 0);
      unsigned short* lb = &Bs[buf][chunk * 512];
      __builtin_amdgcn_global_load_lds(
          (const __attribute__((address_space(1))) void*)(gB + (size_t)r * ldb + cb),
          (__attribute__((address_space(3))) void*)lb, 16, 0, 0);
    }
  };

  f32x4 acc[4][4];
#pragma unroll
  for (int mi = 0; mi < 4; ++mi)
#pragma unroll
    for (int ni = 0; ni < 4; ++ni)
#pragma unroll
      for (int j = 0; j < 4; ++j) acc[mi][ni][j] = 0.f;

  stage(0, 0);
  int cur = 0;
  for (int kt = 0; kt < NKT; ++kt) {
    __syncthreads();                           // drains vmcnt -> buf[cur] ready
    if (kt + 1 < NKT) stage(cur ^ 1, kt + 1);  // prefetch next tile
#pragma unroll
    for (int kc = 0; kc < 2; ++kc) {
      short8 af[4], bfr[4];
#pragma unroll
      for (int mi = 0; mi < 4; ++mi) {
        int row = wm * 64 + mi * 16 + (lane & 15);
        af[mi] = *(const short8*)&As[cur][row * BKK + kc * 32 + ((lane >> 4) * 8)];
      }
#pragma unroll
      for (int ni = 0; ni < 4; ++ni) {
        int row = wn * 64 + ni * 16 + (lane & 15);
        bfr[ni] = *(const short8*)&Bs[cur][row * BKK + kc * 32 + ((lane >> 4) * 8)];
      }
#pragma unroll
      for (int mi = 0; mi < 4; ++mi)
#pragma unroll
        for (int ni = 0; ni < 4; ++ni)
          acc[mi][ni] = __builtin_amdgcn_mfma_f32_16x16x32_bf16(af[mi], bfr[ni], acc[mi][ni], 0, 0, 0);
    }
    cur ^= 1;
  }

  // epilogue: C/D layout col = lane&15, row = (lane>>4)*4 + j
#pragma unroll
  for (int ni = 0; ni < 4; ++ni) {
    int col = n0 + wn * 64 + ni * 16 + (lane & 15);
    float bv = bias[col];
#pragma unroll
    for (int mi = 0; mi < 4; ++mi) {
      int r0 = m0 + wm * 64 + mi * 16 + ((lane >> 4) << 2);
#pragma unroll
      for (int j = 0; j < 4; ++j)
        out[(size_t)(r0 + j) * O_DIM + col] = acc[mi][ni][j] + bv;
    }
  }
}

extern "C" void kernel_launch(void* const* d_in, const int* in_sizes, int n_in,
                              void* d_out, int out_size, void* d_ws, size_t ws_size,
                              hipStream_t stream) {
  const float* x      = (const float*)d_in[0];
  const float* coeffs = (const float*)d_in[1];
  float* out = (float*)d_out;
  char* ws = (char*)d_ws;
  unsigned short* A  = (unsigned short*)ws;                          // 50,331,648 B
  unsigned short* Bt = (unsigned short*)(ws + 50331648);             // 12,582,912 B
  float* bias        = (float*)(ws + 50331648 + 12582912);           // 4,096 B

  k_basis<<<2048, 256, 0, stream>>>(x, A);
  k_coef<<<dim3(32, 32), 256, 0, stream>>>(coeffs, Bt);
  k_bias<<<4, 256, 0, stream>>>(coeffs, bias);
  k_gemm<<<dim3(O_DIM / BN, M_DIM / BM), 256, 0, stream>>>(A, Bt, bias, out);
}

// Round 2
// 164.635 us; speedup vs baseline: 1.7258x; 1.7258x over previous
//
#include <hip/hip_runtime.h>
#include <stdint.h>

#define M_DIM 4096
#define I_DIM 1024
#define O_DIM 1024
#define KB 6
#define K_DIM (I_DIM * KB)   // 6144

typedef __attribute__((ext_vector_type(8))) short short8;
typedef __attribute__((ext_vector_type(4))) float f32x4;
typedef __attribute__((ext_vector_type(4))) unsigned int u32x4;
typedef __attribute__((ext_vector_type(4))) float hfloat4;

__device__ __forceinline__ unsigned short f2bf(float f) {
  union { float f; unsigned int u; } v; v.f = f;
  unsigned int u = v.u;
  unsigned int r = (u + 0x7FFFu + ((u >> 16) & 1u)) >> 16;
  return (unsigned short)r;
}

// ---------------- Kernel 1: basis planes -> bf16 A[4096][6144], k = i*6+j ----
__global__ __launch_bounds__(256) void k_basis(const float* __restrict__ x,
                                               unsigned short* __restrict__ A) {
  int t = blockIdx.x * 256 + threadIdx.x;     // 524288 threads, 8 elements each
  long e0 = (long)t * 8;
  const hfloat4* xp = (const hfloat4*)(x + e0);
  hfloat4 v0 = xp[0], v1 = xp[1];
  float xv[8];
  xv[0]=v0[0]; xv[1]=v0[1]; xv[2]=v0[2]; xv[3]=v0[3];
  xv[4]=v1[0]; xv[5]=v1[1]; xv[6]=v1[2]; xv[7]=v1[3];
  unsigned short outv[48];
#pragma unroll
  for (int e = 0; e < 8; ++e) {
    float s  = 1.0f / (1.0f + __expf(-xv[e]));
    float b2 = s, b3 = s, b4 = s * s;
    float b5 = fmaf(s, b4, b3 + b2 + 1.0f);        // + b1(=1) + b0(=0)
    float b6 = fmaf(s, b5, b4 + b3 + b2 + 1.0f);
    float b7 = fmaf(s, b6, b5 + b4 + b3 + b2);
    float b8 = fmaf(s, b7, b6 + b5 + b4 + b3);
    outv[e*6+0] = f2bf(s);    // carries (c2+c3)
    outv[e*6+1] = f2bf(b4);   // carries c4
    outv[e*6+2] = f2bf(b5);
    outv[e*6+3] = f2bf(b6);
    outv[e*6+4] = f2bf(b7);
    outv[e*6+5] = f2bf(b8);
  }
  u32x4* dst = (u32x4*)(A + e0 * KB);
  const u32x4* srcv = (const u32x4*)outv;
#pragma unroll
  for (int q = 0; q < 6; ++q) dst[q] = srcv[q];
}

// ---------------- Kernel 2: coeffs -> bf16 Bt[1024][6144] (k-contiguous) -----
__global__ __launch_bounds__(256) void k_coef(const float* __restrict__ C,
                                              unsigned short* __restrict__ Bt) {
  __shared__ unsigned short tile[32 * 192];    // [o_local][i_local*6 + j]
  int i0 = blockIdx.x * 32, o0 = blockIdx.y * 32;
  int t = threadIdx.x;
  int ol = t & 31, ig = t >> 5;                // ig: 0..7
#pragma unroll
  for (int r = 0; r < 4; ++r) {
    int il = ig + r * 8;
    const float* p = C + (size_t)(i0 + il) * (O_DIM * 9) + (size_t)(o0 + ol) * 9;
    float c2 = p[2], c3 = p[3], c4 = p[4], c5 = p[5], c6 = p[6], c7 = p[7], c8 = p[8];
    unsigned short* q = &tile[ol * 192 + il * 6];
    q[0] = f2bf(c2 + c3);
    q[1] = f2bf(c4);
    q[2] = f2bf(c5);
    q[3] = f2bf(c6);
    q[4] = f2bf(c7);
    q[5] = f2bf(c8);
  }
  __syncthreads();
  const u32x4* lsrc = (const u32x4*)tile;      // 768 chunks of 16B
#pragma unroll
  for (int r = 0; r < 3; ++r) {
    int c = t + r * 256;
    int row = c / 24, off = c % 24;
    u32x4* gdst = (u32x4*)(Bt + (size_t)(o0 + row) * K_DIM + (size_t)i0 * 6 + off * 8);
    *gdst = lsrc[c];
  }
}

// ---------------- Kernel 2b: bias[o] = sum_i c[i][o][1], parallel ------------
__global__ __launch_bounds__(256) void k_bias(const float* __restrict__ C,
                                              float* __restrict__ bias) {
  __shared__ float red[256];
  int o = blockIdx.x;                          // 1024 blocks
  int t = threadIdx.x;
  float s = 0.f;
#pragma unroll
  for (int r = 0; r < 4; ++r) {
    int i = t + r * 256;
    s += C[(size_t)i * (O_DIM * 9) + (size_t)o * 9 + 1];
  }
  red[t] = s;
  __syncthreads();
#pragma unroll
  for (int w = 128; w > 0; w >>= 1) {
    if (t < w) red[t] += red[t + w];
    __syncthreads();
  }
  if (t == 0) bias[o] = red[0];
}

// ---------------- Kernel 3: bf16 GEMM, 128x128 tile, BK=32, split-K ----------
#define BM 128
#define BN 128
#define BKK 32
#define SPLITS 4

template<bool SPLIT>
__global__ __launch_bounds__(256) void k_gemm(const unsigned short* __restrict__ A,
                                              const unsigned short* __restrict__ Bt,
                                              const float* __restrict__ bias,
                                              float* __restrict__ dst) {
  constexpr int CK  = SPLIT ? (K_DIM / SPLITS) : K_DIM;   // 1536 or 6144
  constexpr int NKT = CK / BKK;                           // 48 or 192
  __shared__ unsigned short As[2][BM * BKK];   // 8 KB each
  __shared__ unsigned short Bs[2][BN * BKK];
  int tid = threadIdx.x;
  int wid = tid >> 6, lane = tid & 63;
  int m0 = blockIdx.y * BM, n0 = blockIdx.x * BN;
  size_t kbase = (size_t)blockIdx.z * CK;
  int wm = wid >> 1, wn = wid & 1;

  auto stage = [&](int buf, int kt) {
    const unsigned short* gA = A + (size_t)m0 * K_DIM + kbase + (size_t)kt * BKK;
    const unsigned short* gB = Bt + (size_t)n0 * K_DIM + kbase + (size_t)kt * BKK;
#pragma unroll
    for (int c = 0; c < 2; ++c) {
      int chunk = wid * 2 + c;                 // 0..7, 1KB each (16 rows x 64B)
      int r  = chunk * 16 + (lane >> 2);       // tile row
      int cu = (lane & 3) * 8;                 // ushort offset within 32-wide row
      __builtin_amdgcn_global_load_lds(
          (const __attribute__((address_space(1))) void*)(gA + (size_t)r * K_DIM + cu),
          (__attribute__((address_space(3))) void*)&As[buf][chunk * 512], 16, 0, 0);
      __builtin_amdgcn_global_load_lds(
          (const __attribute__((address_space(1))) void*)(gB + (size_t)r * K_DIM + cu),
          (__attribute__((address_space(3))) void*)&Bs[buf][chunk * 512], 16, 0, 0);
    }
  };

  f32x4 acc[4][4];
#pragma unroll
  for (int mi = 0; mi < 4; ++mi)
#pragma unroll
    for (int ni = 0; ni < 4; ++ni)
#pragma unroll
      for (int j = 0; j < 4; ++j) acc[mi][ni][j] = 0.f;

  stage(0, 0);
  int cur = 0;
  for (int kt = 0; kt < NKT; ++kt) {
    __syncthreads();                           // compiler drains vmcnt before barrier
    if (kt + 1 < NKT) stage(cur ^ 1, kt + 1);
    short8 af[4], bfr[4];
#pragma unroll
    for (int mi = 0; mi < 4; ++mi) {
      int row = wm * 64 + mi * 16 + (lane & 15);
      af[mi] = *(const short8*)&As[cur][row * BKK + ((lane >> 4) * 8)];
    }
#pragma unroll
    for (int ni = 0; ni < 4; ++ni) {
      int row = wn * 64 + ni * 16 + (lane & 15);
      bfr[ni] = *(const short8*)&Bs[cur][row * BKK + ((lane >> 4) * 8)];
    }
#pragma unroll
    for (int mi = 0; mi < 4; ++mi)
#pragma unroll
      for (int ni = 0; ni < 4; ++ni)
        acc[mi][ni] = __builtin_amdgcn_mfma_f32_16x16x32_bf16(af[mi], bfr[ni], acc[mi][ni], 0, 0, 0);
    cur ^= 1;
  }

  // epilogue: C/D layout col = lane&15, row = (lane>>4)*4 + j
  float* base = SPLIT ? (dst + (size_t)blockIdx.z * ((size_t)M_DIM * O_DIM)) : dst;
#pragma unroll
  for (int ni = 0; ni < 4; ++ni) {
    int col = n0 + wn * 64 + ni * 16 + (lane & 15);
    float bv = SPLIT ? 0.f : bias[col];
#pragma unroll
    for (int mi = 0; mi < 4; ++mi) {
      int r0 = m0 + wm * 64 + mi * 16 + ((lane >> 4) << 2);
#pragma unroll
      for (int j = 0; j < 4; ++j)
        base[(size_t)(r0 + j) * O_DIM + col] = acc[mi][ni][j] + bv;
    }
  }
}

// ---------------- Kernel 4: reduce split-K partials + bias -------------------
__global__ __launch_bounds__(256) void k_reduce(const float* __restrict__ part,
                                                const float* __restrict__ bias,
                                                float* __restrict__ out) {
  size_t t = (size_t)blockIdx.x * 256 + threadIdx.x;   // 1M threads, 4 outputs each
  size_t idx = t * 4;
  const size_t P = (size_t)M_DIM * O_DIM;
  f32x4 s0 = *(const f32x4*)(part + idx);
  f32x4 s1 = *(const f32x4*)(part + P + idx);
  f32x4 s2 = *(const f32x4*)(part + 2 * P + idx);
  f32x4 s3 = *(const f32x4*)(part + 3 * P + idx);
  f32x4 bv = *(const f32x4*)(bias + (idx & (O_DIM - 1)));
  f32x4 r;
#pragma unroll
  for (int j = 0; j < 4; ++j) r[j] = ((s0[j] + s1[j]) + (s2[j] + s3[j])) + bv[j];
  *(f32x4*)(out + idx) = r;
}

extern "C" void kernel_launch(void* const* d_in, const int* in_sizes, int n_in,
                              void* d_out, int out_size, void* d_ws, size_t ws_size,
                              hipStream_t stream) {
  const float* x      = (const float*)d_in[0];
  const float* coeffs = (const float*)d_in[1];
  float* out = (float*)d_out;
  char* ws = (char*)d_ws;
  const size_t offA    = 0;
  const size_t offB    = 50331648;                 // A: 4096*6144*2
  const size_t offBias = offB + 12582912;          // Bt: 1024*6144*2
  const size_t offPart = offBias + 4096;
  const size_t needSplit = offPart + (size_t)SPLITS * M_DIM * O_DIM * 4;  // ~130 MB

  unsigned short* A  = (unsigned short*)(ws + offA);
  unsigned short* Bt = (unsigned short*)(ws + offB);
  float* bias        = (float*)(ws + offBias);
  float* part        = (float*)(ws + offPart);

  k_basis<<<2048, 256, 0, stream>>>(x, A);
  k_coef<<<dim3(32, 32), 256, 0, stream>>>(coeffs, Bt);
  k_bias<<<1024, 256, 0, stream>>>(coeffs, bias);

  if (ws_size >= needSplit) {
    k_gemm<true><<<dim3(O_DIM / BN, M_DIM / BM, SPLITS), 256, 0, stream>>>(A, Bt, bias, part);
    k_reduce<<<(M_DIM * O_DIM) / (256 * 4), 256, 0, stream>>>(part, bias, out);
  } else {
    k_gemm<false><<<dim3(O_DIM / BN, M_DIM / BM, 1), 256, 0, stream>>>(A, Bt, bias, out);
  }
}

// Round 3
// 119.120 us; speedup vs baseline: 2.3852x; 1.3821x over previous
//
#include <hip/hip_runtime.h>
#include <stdint.h>

#define M_DIM 4096
#define I_DIM 1024
#define O_DIM 1024
#define KB 6
#define K_DIM (I_DIM * KB)   // 6144
#define SPLITS 4

typedef __attribute__((ext_vector_type(8))) short short8;
typedef __attribute__((ext_vector_type(4))) float f32x4;
typedef __attribute__((ext_vector_type(4))) unsigned int u32x4;
typedef __attribute__((ext_vector_type(4))) float hfloat4;

__device__ __forceinline__ unsigned short f2bf(float f) {
  union { float f; unsigned int u; } v; v.f = f;
  unsigned int u = v.u;
  unsigned int r = (u + 0x7FFFu + ((u >> 16) & 1u)) >> 16;
  return (unsigned short)r;
}

// ---------------- Kernel 1: basis planes -> bf16 A[4096][6144], k = i*6+j ----
__global__ __launch_bounds__(256) void k_basis(const float* __restrict__ x,
                                               unsigned short* __restrict__ A) {
  int t = blockIdx.x * 256 + threadIdx.x;
  long e0 = (long)t * 8;
  const hfloat4* xp = (const hfloat4*)(x + e0);
  hfloat4 v0 = xp[0], v1 = xp[1];
  float xv[8];
  xv[0]=v0[0]; xv[1]=v0[1]; xv[2]=v0[2]; xv[3]=v0[3];
  xv[4]=v1[0]; xv[5]=v1[1]; xv[6]=v1[2]; xv[7]=v1[3];
  unsigned short outv[48];
#pragma unroll
  for (int e = 0; e < 8; ++e) {
    float s  = 1.0f / (1.0f + __expf(-xv[e]));
    float b2 = s, b3 = s, b4 = s * s;
    float b5 = fmaf(s, b4, b3 + b2 + 1.0f);
    float b6 = fmaf(s, b5, b4 + b3 + b2 + 1.0f);
    float b7 = fmaf(s, b6, b5 + b4 + b3 + b2);
    float b8 = fmaf(s, b7, b6 + b5 + b4 + b3);
    outv[e*6+0] = f2bf(s);
    outv[e*6+1] = f2bf(b4);
    outv[e*6+2] = f2bf(b5);
    outv[e*6+3] = f2bf(b6);
    outv[e*6+4] = f2bf(b7);
    outv[e*6+5] = f2bf(b8);
  }
  u32x4* dst = (u32x4*)(A + e0 * KB);
  const u32x4* srcv = (const u32x4*)outv;
#pragma unroll
  for (int q = 0; q < 6; ++q) dst[q] = srcv[q];
}

// ---------------- Kernel 2: coeffs -> bf16 Bt[1024][6144] (k-contiguous) -----
__global__ __launch_bounds__(256) void k_coef(const float* __restrict__ C,
                                              unsigned short* __restrict__ Bt) {
  __shared__ unsigned short tile[32 * 192];
  int i0 = blockIdx.x * 32, o0 = blockIdx.y * 32;
  int t = threadIdx.x;
  int ol = t & 31, ig = t >> 5;
#pragma unroll
  for (int r = 0; r < 4; ++r) {
    int il = ig + r * 8;
    const float* p = C + (size_t)(i0 + il) * (O_DIM * 9) + (size_t)(o0 + ol) * 9;
    float c2 = p[2], c3 = p[3], c4 = p[4], c5 = p[5], c6 = p[6], c7 = p[7], c8 = p[8];
    unsigned short* q = &tile[ol * 192 + il * 6];
    q[0] = f2bf(c2 + c3);
    q[1] = f2bf(c4);
    q[2] = f2bf(c5);
    q[3] = f2bf(c6);
    q[4] = f2bf(c7);
    q[5] = f2bf(c8);
  }
  __syncthreads();
  const u32x4* lsrc = (const u32x4*)tile;
#pragma unroll
  for (int r = 0; r < 3; ++r) {
    int c = t + r * 256;
    int row = c / 24, off = c % 24;
    u32x4* gdst = (u32x4*)(Bt + (size_t)(o0 + row) * K_DIM + (size_t)i0 * 6 + off * 8);
    *gdst = lsrc[c];
  }
}

// ---------------- Kernel 2b: bias[o] = sum_i c[i][o][1], parallel ------------
__global__ __launch_bounds__(256) void k_bias(const float* __restrict__ C,
                                              float* __restrict__ bias) {
  __shared__ float red[256];
  int o = blockIdx.x;
  int t = threadIdx.x;
  float s = 0.f;
#pragma unroll
  for (int r = 0; r < 4; ++r) {
    int i = t + r * 256;
    s += C[(size_t)i * (O_DIM * 9) + (size_t)o * 9 + 1];
  }
  red[t] = s;
  __syncthreads();
#pragma unroll
  for (int w = 128; w > 0; w >>= 1) {
    if (t < w) red[t] += red[t + w];
    __syncthreads();
  }
  if (t == 0) bias[o] = red[0];
}

// ---------------- Kernel 3: 256x256 8-phase bf16 GEMM (T2+T3+T4+T5) ----------
// 512 thr = 8 waves (2M x 4N); per-wave C = 128x64. BK=64, LDS dbuf 128KB.
// LDS tile layout: [256 rows][64 k] bf16, 16B-chunk c swizzled c^=(row&7).
#define SBAR __builtin_amdgcn_sched_barrier(0)

template<bool SPLIT>
__global__ __launch_bounds__(512, 2) void k_gemm8(const unsigned short* __restrict__ A,
                                                  const unsigned short* __restrict__ B,
                                                  const float* __restrict__ bias,
                                                  float* __restrict__ dst) {
  constexpr int CK = SPLIT ? (K_DIM / SPLITS) : K_DIM;   // 1536 / 6144
  constexpr int NT = CK / 64;                            // 24 / 96
  __shared__ char lds[131072];   // [2 buf][A 32KB | B 32KB]
  const int tid = threadIdx.x;
  const int lane = tid & 63, wid = tid >> 6;
  const int wm = wid >> 2, wn = wid & 3;
  const int l15 = lane & 15, lk = lane >> 4, l7 = lane & 7;
  const int m0 = blockIdx.y * 256, n0 = blockIdx.x * 256;
  const size_t kb = (size_t)blockIdx.z * CK;
  // staging: thread tid covers LDS rows tid>>3 (+64), chunk slot tid&7;
  // pre-swizzled global chunk = slot ^ (row&7)
  const int srow = tid >> 3;
  const int cg8 = (((tid & 7) ^ ((tid >> 3) & 7)) * 8);  // ushort offset
  // ds_read swizzled chunk offsets (row&7 == lane&7 for all frags)
  const int cx0 = (lk ^ l7) * 16;
  const int cx1 = ((4 + lk) ^ l7) * 16;
  const int arow = wm * 128 + l15;
  const int brow = wn * 64 + l15;

  auto gload = [&](const unsigned short* s, int ldsoff) {
    __builtin_amdgcn_global_load_lds((const __attribute__((address_space(1))) void*)s,
        (__attribute__((address_space(3))) void*)(lds + ldsoff), 16, 0, 0);
  };
  auto stageA = [&](int buf, int h, int kt2) {
    const unsigned short* s = A + (size_t)(m0 + h * 128 + srow) * K_DIM + kb + (size_t)kt2 * 64 + cg8;
    int d = buf * 65536 + h * 16384 + tid * 16;
    gload(s, d);
    gload(s + (size_t)64 * K_DIM, d + 8192);
  };
  auto stageB = [&](int buf, int h, int kt2) {
    const unsigned short* s = B + (size_t)(n0 + h * 128 + srow) * K_DIM + kb + (size_t)kt2 * 64 + cg8;
    int d = buf * 65536 + 32768 + h * 16384 + tid * 16;
    gload(s, d);
    gload(s + (size_t)64 * K_DIM, d + 8192);
  };

  short8 af[4][2], bf0[2][2], bf1[2][2];
  f32x4 acc[8][4];
#pragma unroll
  for (int i = 0; i < 8; ++i)
#pragma unroll
    for (int n = 0; n < 4; ++n)
#pragma unroll
      for (int j = 0; j < 4; ++j) acc[i][n][j] = 0.f;

  auto loadA = [&](int buf, int h) {
#pragma unroll
    for (int mm = 0; mm < 4; ++mm) {
      int rb = buf * 65536 + (arow + h * 64 + mm * 16) * 128;
      af[mm][0] = *(const short8*)(lds + rb + cx0);
      af[mm][1] = *(const short8*)(lds + rb + cx1);
    }
  };
  auto loadB = [&](int buf, int g, short8 (&bfx)[2][2]) {
#pragma unroll
    for (int nn = 0; nn < 2; ++nn) {
      int rb = buf * 65536 + 32768 + (brow + g * 32 + nn * 16) * 128;
      bfx[nn][0] = *(const short8*)(lds + rb + cx0);
      bfx[nn][1] = *(const short8*)(lds + rb + cx1);
    }
  };
  auto quad = [&](int h, int g, short8 (&bfx)[2][2]) {
#pragma unroll
    for (int mm = 0; mm < 4; ++mm)
#pragma unroll
      for (int nn = 0; nn < 2; ++nn)
#pragma unroll
        for (int kc = 0; kc < 2; ++kc)
          acc[h * 4 + mm][g * 2 + nn] =
              __builtin_amdgcn_mfma_f32_16x16x32_bf16(af[mm][kc], bfx[nn][kc],
                                                      acc[h * 4 + mm][g * 2 + nn], 0, 0, 0);
  };
  auto preMFMA = [&]() {
    SBAR; __builtin_amdgcn_s_barrier();
    asm volatile("s_waitcnt lgkmcnt(0)" ::: "memory"); SBAR;
    __builtin_amdgcn_s_setprio(1);
  };
  auto postMFMA = [&]() {
    __builtin_amdgcn_s_setprio(0); SBAR;
    __builtin_amdgcn_s_barrier(); SBAR;
  };

  // prologue: tile0 fully + tile1 B-halves; keep tile1.B in flight (vmcnt 4)
  stageA(0, 0, 0); stageA(0, 1, 0); stageB(0, 0, 0); stageB(0, 1, 0);
  stageB(1, 0, 1); stageB(1, 1, 1);
  asm volatile("s_waitcnt vmcnt(4)" ::: "memory"); SBAR;
  __builtin_amdgcn_s_barrier(); SBAR;

#pragma unroll 1
  for (int kt = 0; kt < NT; ++kt) {
    const int buf = kt & 1, nb = buf ^ 1;
    // ph0: read A(h0)+B(g0); stage (t+1).A1
    loadA(buf, 0); loadB(buf, 0, bf0);
    if (kt + 1 < NT) stageA(nb, 1, kt + 1);
    preMFMA(); quad(0, 0, bf0); postMFMA();
    // ph1: read B(g1); stage (t+1).A0
    loadB(buf, 1, bf1);
    if (kt + 1 < NT) stageA(nb, 0, kt + 1);
    preMFMA(); quad(0, 1, bf1); postMFMA();
    // ph2: read A(h1); stage (t+2).B0 (B0 region free after ph1)
    loadA(buf, 1);
    if (kt + 2 < NT) stageB(buf, 0, kt + 2);
    preMFMA(); quad(1, 1, bf1); postMFMA();
    // ph3: no reads; stage (t+2).B1; boundary counted-vmcnt
    if (kt + 2 < NT) stageB(buf, 1, kt + 2);
    SBAR; __builtin_amdgcn_s_barrier();
    asm volatile("s_waitcnt lgkmcnt(0)" ::: "memory"); SBAR;
    __builtin_amdgcn_s_setprio(1); quad(1, 0, bf0); __builtin_amdgcn_s_setprio(0); SBAR;
    if (kt + 1 < NT) {
      if (kt + 2 < NT) asm volatile("s_waitcnt vmcnt(4)" ::: "memory");
      else             asm volatile("s_waitcnt vmcnt(0)" ::: "memory");
      SBAR;
      __builtin_amdgcn_s_barrier(); SBAR;
    }
  }

  // epilogue: C/D layout col = lane&15, row = (lane>>4)*4 + j
  float* base = SPLIT ? (dst + (size_t)blockIdx.z * ((size_t)M_DIM * O_DIM)) : dst;
#pragma unroll
  for (int mi = 0; mi < 8; ++mi) {
    int r0 = m0 + wm * 128 + mi * 16 + (lk << 2);
#pragma unroll
    for (int ni = 0; ni < 4; ++ni) {
      int col = n0 + wn * 64 + ni * 16 + l15;
      float bv = SPLIT ? 0.f : bias[col];
#pragma unroll
      for (int j = 0; j < 4; ++j)
        base[(size_t)(r0 + j) * O_DIM + col] = acc[mi][ni][j] + bv;
    }
  }
}

// ---------------- Kernel 4: reduce split-K partials + bias -------------------
__global__ __launch_bounds__(256) void k_reduce(const float* __restrict__ part,
                                                const float* __restrict__ bias,
                                                float* __restrict__ out) {
  size_t t = (size_t)blockIdx.x * 256 + threadIdx.x;
  size_t idx = t * 4;
  const size_t P = (size_t)M_DIM * O_DIM;
  f32x4 s0 = *(const f32x4*)(part + idx);
  f32x4 s1 = *(const f32x4*)(part + P + idx);
  f32x4 s2 = *(const f32x4*)(part + 2 * P + idx);
  f32x4 s3 = *(const f32x4*)(part + 3 * P + idx);
  f32x4 bv = *(const f32x4*)(bias + (idx & (O_DIM - 1)));
  f32x4 r;
#pragma unroll
  for (int j = 0; j < 4; ++j) r[j] = ((s0[j] + s1[j]) + (s2[j] + s3[j])) + bv[j];
  *(f32x4*)(out + idx) = r;
}

extern "C" void kernel_launch(void* const* d_in, const int* in_sizes, int n_in,
                              void* d_out, int out_size, void* d_ws, size_t ws_size,
                              hipStream_t stream) {
  const float* x      = (const float*)d_in[0];
  const float* coeffs = (const float*)d_in[1];
  float* out = (float*)d_out;
  char* ws = (char*)d_ws;
  const size_t offA    = 0;
  const size_t offB    = 50331648;                 // A: 4096*6144*2
  const size_t offBias = offB + 12582912;          // Bt: 1024*6144*2
  const size_t offPart = offBias + 4096;
  const size_t needSplit = offPart + (size_t)SPLITS * M_DIM * O_DIM * 4;

  unsigned short* A  = (unsigned short*)(ws + offA);
  unsigned short* Bt = (unsigned short*)(ws + offB);
  float* bias        = (float*)(ws + offBias);
  float* part        = (float*)(ws + offPart);

  k_basis<<<2048, 256, 0, stream>>>(x, A);
  k_coef<<<dim3(32, 32), 256, 0, stream>>>(coeffs, Bt);
  k_bias<<<1024, 256, 0, stream>>>(coeffs, bias);

  if (ws_size >= needSplit) {
    k_gemm8<true><<<dim3(O_DIM / 256, M_DIM / 256, SPLITS), 512, 0, stream>>>(A, Bt, bias, part);
    k_reduce<<<(M_DIM * O_DIM) / (256 * 4), 256, 0, stream>>>(part, bias, out);
  } else {
    k_gemm8<false><<<dim3(O_DIM / 256, M_DIM / 256, 1), 512, 0, stream>>>(A, Bt, bias, out);
  }
}

// Round 4
// 95.607 us; speedup vs baseline: 2.9718x; 1.2459x over previous
//
#include <hip/hip_runtime.h>
#include <stdint.h>

#define M_DIM 4096
#define I_DIM 1024
#define O_DIM 1024
#define KB 6
#define K_DIM (I_DIM * KB)   // 6144
#define SPLITS 4

typedef __attribute__((ext_vector_type(8))) short short8;
typedef __attribute__((ext_vector_type(4))) float f32x4;
typedef __attribute__((ext_vector_type(4))) unsigned int u32x4;
typedef __attribute__((ext_vector_type(4))) float hfloat4;

__device__ __forceinline__ unsigned short f2bf(float f) {
  union { float f; unsigned int u; } v; v.f = f;
  unsigned int u = v.u;
  unsigned int r = (u + 0x7FFFu + ((u >> 16) & 1u)) >> 16;
  return (unsigned short)r;
}

// ---------------- Kernel 1: basis planes -> bf16 A[4096][6144], k = i*6+j ----
__global__ __launch_bounds__(256) void k_basis(const float* __restrict__ x,
                                               unsigned short* __restrict__ A) {
  int t = blockIdx.x * 256 + threadIdx.x;
  long e0 = (long)t * 8;
  const hfloat4* xp = (const hfloat4*)(x + e0);
  hfloat4 v0 = xp[0], v1 = xp[1];
  float xv[8];
  xv[0]=v0[0]; xv[1]=v0[1]; xv[2]=v0[2]; xv[3]=v0[3];
  xv[4]=v1[0]; xv[5]=v1[1]; xv[6]=v1[2]; xv[7]=v1[3];
  unsigned short outv[48];
#pragma unroll
  for (int e = 0; e < 8; ++e) {
    float s  = 1.0f / (1.0f + __expf(-xv[e]));
    float b2 = s, b3 = s, b4 = s * s;
    float b5 = fmaf(s, b4, b3 + b2 + 1.0f);
    float b6 = fmaf(s, b5, b4 + b3 + b2 + 1.0f);
    float b7 = fmaf(s, b6, b5 + b4 + b3 + b2);
    float b8 = fmaf(s, b7, b6 + b5 + b4 + b3);
    outv[e*6+0] = f2bf(s);
    outv[e*6+1] = f2bf(b4);
    outv[e*6+2] = f2bf(b5);
    outv[e*6+3] = f2bf(b6);
    outv[e*6+4] = f2bf(b7);
    outv[e*6+5] = f2bf(b8);
  }
  u32x4* dst = (u32x4*)(A + e0 * KB);
  const u32x4* srcv = (const u32x4*)outv;
#pragma unroll
  for (int q = 0; q < 6; ++q) dst[q] = srcv[q];
}

// ---- Kernel 2: coeffs -> bf16 Bt[1024][6144] + per-i-block bias partials ----
__global__ __launch_bounds__(256) void k_coef(const float* __restrict__ C,
                                              unsigned short* __restrict__ Bt,
                                              float* __restrict__ partB) {
  __shared__ unsigned short tile[32 * 192];
  __shared__ float bred[256];
  int i0 = blockIdx.x * 32, o0 = blockIdx.y * 32;
  int t = threadIdx.x;
  int ol = t & 31, ig = t >> 5;
  float bsum = 0.f;
#pragma unroll
  for (int r = 0; r < 4; ++r) {
    int il = ig + r * 8;
    const float* p = C + (size_t)(i0 + il) * (O_DIM * 9) + (size_t)(o0 + ol) * 9;
    float c1 = p[1];
    float c2 = p[2], c3 = p[3], c4 = p[4], c5 = p[5], c6 = p[6], c7 = p[7], c8 = p[8];
    bsum += c1;
    unsigned short* q = &tile[ol * 192 + il * 6];
    q[0] = f2bf(c2 + c3);
    q[1] = f2bf(c4);
    q[2] = f2bf(c5);
    q[3] = f2bf(c6);
    q[4] = f2bf(c7);
    q[5] = f2bf(c8);
  }
  bred[t] = bsum;
  __syncthreads();
  if (t < 32) {
    float s = 0.f;
#pragma unroll
    for (int g = 0; g < 8; ++g) s += bred[g * 32 + t];
    partB[(size_t)blockIdx.x * O_DIM + o0 + t] = s;
  }
  const u32x4* lsrc = (const u32x4*)tile;
#pragma unroll
  for (int r = 0; r < 3; ++r) {
    int c = t + r * 256;
    int row = c / 24, off = c % 24;
    u32x4* gdst = (u32x4*)(Bt + (size_t)(o0 + row) * K_DIM + (size_t)i0 * 6 + off * 8);
    *gdst = lsrc[c];
  }
}

// ---------------- Kernel 2b: final bias reduce (32 partials) -----------------
__global__ __launch_bounds__(256) void k_bias2(const float* __restrict__ partB,
                                               float* __restrict__ bias) {
  int o = blockIdx.x * 256 + threadIdx.x;     // 4 blocks
  float s = 0.f;
#pragma unroll
  for (int ib = 0; ib < 32; ++ib) s += partB[(size_t)ib * O_DIM + o];
  bias[o] = s;
}

// ---------------- Kernel 3: 256x256 8-phase bf16 GEMM (T2+T3+T4+T5) ----------
// 512 thr = 8 waves (2M x 4N); per-wave C = 128x64. BK=64, LDS dbuf 128KB.
// v2: 1 barrier/phase (WAR carried by phase p+1 barrier), XCD panel grouping.
#define SBAR __builtin_amdgcn_sched_barrier(0)

template<bool SPLIT>
__global__ __launch_bounds__(512, 2) void k_gemm8(const unsigned short* __restrict__ A,
                                                  const unsigned short* __restrict__ B,
                                                  const float* __restrict__ bias,
                                                  float* __restrict__ dst) {
  constexpr int CK = SPLIT ? (K_DIM / SPLITS) : K_DIM;   // 1536 / 6144
  constexpr int NT = CK / 64;                            // 24 / 96
  constexpr int PPX = SPLIT ? 8 : 2;                     // (y,z) panels per XCD
  __shared__ char lds[131072];   // [2 buf][A 32KB | B 32KB]
  const int tid = threadIdx.x;
  const int lane = tid & 63, wid = tid >> 6;
  const int wm = wid >> 2, wn = wid & 3;
  const int l15 = lane & 15, lk = lane >> 4, l7 = lane & 7;
  // XCD-grouped bijective remap: 4 n-blocks of one (ym,zk) panel -> same XCD
  const int flat = blockIdx.x + (blockIdx.y << 2) + (blockIdx.z << 6);
  const int xcd = flat & 7, slot = flat >> 3;
  const int panel = xcd * PPX + (slot >> 2);
  const int xn = slot & 3;
  const int ym = panel & 15, zk = panel >> 4;
  const int m0 = ym * 256, n0 = xn * 256;
  const size_t kb = (size_t)zk * CK;
  // staging: thread tid covers LDS rows tid>>3 (+64), chunk slot tid&7;
  // pre-swizzled global chunk = slot ^ (row&7)
  const int srow = tid >> 3;
  const int cg8 = (((tid & 7) ^ ((tid >> 3) & 7)) * 8);  // ushort offset
  // ds_read swizzled chunk offsets (row&7 == lane&7 for all frags)
  const int cx0 = (lk ^ l7) * 16;
  const int cx1 = ((4 + lk) ^ l7) * 16;
  const int arow = wm * 128 + l15;
  const int brow = wn * 64 + l15;

  auto gload = [&](const unsigned short* s, int ldsoff) {
    __builtin_amdgcn_global_load_lds((const __attribute__((address_space(1))) void*)s,
        (__attribute__((address_space(3))) void*)(lds + ldsoff), 16, 0, 0);
  };
  auto stageA = [&](int buf, int h, int kt2) {
    const unsigned short* s = A + (size_t)(m0 + h * 128 + srow) * K_DIM + kb + (size_t)kt2 * 64 + cg8;
    int d = buf * 65536 + h * 16384 + tid * 16;
    gload(s, d);
    gload(s + (size_t)64 * K_DIM, d + 8192);
  };
  auto stageB = [&](int buf, int h, int kt2) {
    const unsigned short* s = B + (size_t)(n0 + h * 128 + srow) * K_DIM + kb + (size_t)kt2 * 64 + cg8;
    int d = buf * 65536 + 32768 + h * 16384 + tid * 16;
    gload(s, d);
    gload(s + (size_t)64 * K_DIM, d + 8192);
  };

  short8 af[4][2], bf0[2][2], bf1[2][2];
  f32x4 acc[8][4];
#pragma unroll
  for (int i = 0; i < 8; ++i)
#pragma unroll
    for (int n = 0; n < 4; ++n)
#pragma unroll
      for (int j = 0; j < 4; ++j) acc[i][n][j] = 0.f;

  auto loadA = [&](int buf, int h) {
#pragma unroll
    for (int mm = 0; mm < 4; ++mm) {
      int rb = buf * 65536 + (arow + h * 64 + mm * 16) * 128;
      af[mm][0] = *(const short8*)(lds + rb + cx0);
      af[mm][1] = *(const short8*)(lds + rb + cx1);
    }
  };
  auto loadB = [&](int buf, int g, short8 (&bfx)[2][2]) {
#pragma unroll
    for (int nn = 0; nn < 2; ++nn) {
      int rb = buf * 65536 + 32768 + (brow + g * 32 + nn * 16) * 128;
      bfx[nn][0] = *(const short8*)(lds + rb + cx0);
      bfx[nn][1] = *(const short8*)(lds + rb + cx1);
    }
  };
  auto quad = [&](int h, int g, short8 (&bfx)[2][2]) {
#pragma unroll
    for (int mm = 0; mm < 4; ++mm)
#pragma unroll
      for (int nn = 0; nn < 2; ++nn)
#pragma unroll
        for (int kc = 0; kc < 2; ++kc)
          acc[h * 4 + mm][g * 2 + nn] =
              __builtin_amdgcn_mfma_f32_16x16x32_bf16(af[mm][kc], bfx[nn][kc],
                                                      acc[h * 4 + mm][g * 2 + nn], 0, 0, 0);
  };
  auto sync1 = [&]() {   // single barrier per phase, then drain ds_reads
    SBAR; __builtin_amdgcn_s_barrier();
    asm volatile("s_waitcnt lgkmcnt(0)" ::: "memory"); SBAR;
    __builtin_amdgcn_s_setprio(1);
  };
  auto endp = [&]() {    // NO barrier: next phase's ds_reads overlap others' MFMA
    __builtin_amdgcn_s_setprio(0); SBAR;
  };

  // prologue: tile0 fully + tile1 B-halves; keep tile1.B in flight (vmcnt 4)
  stageA(0, 0, 0); stageA(0, 1, 0); stageB(0, 0, 0); stageB(0, 1, 0);
  stageB(1, 0, 1); stageB(1, 1, 1);
  asm volatile("s_waitcnt vmcnt(4)" ::: "memory"); SBAR;
  __builtin_amdgcn_s_barrier(); SBAR;

#pragma unroll 1
  for (int kt = 0; kt < NT; ++kt) {
    const int buf = kt & 1, nb = buf ^ 1;
    // ph0: read A(h0)+B(g0); stage (t+1).A1
    loadA(buf, 0); loadB(buf, 0, bf0);
    if (kt + 1 < NT) stageA(nb, 1, kt + 1);
    sync1(); quad(0, 0, bf0); endp();
    // ph1: read B(g1); stage (t+1).A0
    loadB(buf, 1, bf1);
    if (kt + 1 < NT) stageA(nb, 0, kt + 1);
    sync1(); quad(0, 1, bf1); endp();
    // ph2: read A(h1); stage (t+2).B0 (B0 last read ph0; ph1 barrier orders)
    loadA(buf, 1);
    if (kt + 2 < NT) stageB(buf, 0, kt + 2);
    sync1(); quad(1, 1, bf1); endp();
    // ph3: stage (t+2).B1 (B1 last read ph1; ph2 barrier orders)
    if (kt + 2 < NT) stageB(buf, 1, kt + 2);
    sync1(); quad(1, 0, bf0); endp();
    // tile boundary: counted vmcnt -> next buf valid after barrier
    if (kt + 1 < NT) {
      if (kt + 2 < NT) asm volatile("s_waitcnt vmcnt(4)" ::: "memory");
      else             asm volatile("s_waitcnt vmcnt(0)" ::: "memory");
      SBAR;
      __builtin_amdgcn_s_barrier(); SBAR;
    }
  }

  // epilogue: C/D layout col = lane&15, row = (lane>>4)*4 + j
  float* base = SPLIT ? (dst + (size_t)zk * ((size_t)M_DIM * O_DIM)) : dst;
#pragma unroll
  for (int mi = 0; mi < 8; ++mi) {
    int r0 = m0 + wm * 128 + mi * 16 + (lk << 2);
#pragma unroll
    for (int ni = 0; ni < 4; ++ni) {
      int col = n0 + wn * 64 + ni * 16 + l15;
      float bv = SPLIT ? 0.f : bias[col];
#pragma unroll
      for (int j = 0; j < 4; ++j)
        base[(size_t)(r0 + j) * O_DIM + col] = acc[mi][ni][j] + bv;
    }
  }
}

// ---------------- Kernel 4: reduce split-K partials + bias -------------------
__global__ __launch_bounds__(256) void k_reduce(const float* __restrict__ part,
                                                const float* __restrict__ bias,
                                                float* __restrict__ out) {
  size_t t = (size_t)blockIdx.x * 256 + threadIdx.x;
  size_t idx = t * 4;
  const size_t P = (size_t)M_DIM * O_DIM;
  f32x4 s0 = *(const f32x4*)(part + idx);
  f32x4 s1 = *(const f32x4*)(part + P + idx);
  f32x4 s2 = *(const f32x4*)(part + 2 * P + idx);
  f32x4 s3 = *(const f32x4*)(part + 3 * P + idx);
  f32x4 bv = *(const f32x4*)(bias + (idx & (O_DIM - 1)));
  f32x4 r;
#pragma unroll
  for (int j = 0; j < 4; ++j) r[j] = ((s0[j] + s1[j]) + (s2[j] + s3[j])) + bv[j];
  *(f32x4*)(out + idx) = r;
}

extern "C" void kernel_launch(void* const* d_in, const int* in_sizes, int n_in,
                              void* d_out, int out_size, void* d_ws, size_t ws_size,
                              hipStream_t stream) {
  const float* x      = (const float*)d_in[0];
  const float* coeffs = (const float*)d_in[1];
  float* out = (float*)d_out;
  char* ws = (char*)d_ws;
  const size_t offA     = 0;
  const size_t offB     = 50331648;                // A: 4096*6144*2
  const size_t offBias  = offB + 12582912;         // Bt: 1024*6144*2
  const size_t offPartB = offBias + 4096;          // bias: 1024*4
  const size_t offPart  = offPartB + 131072;       // partB: 32*1024*4
  const size_t needSplit = offPart + (size_t)SPLITS * M_DIM * O_DIM * 4;

  unsigned short* A  = (unsigned short*)(ws + offA);
  unsigned short* Bt = (unsigned short*)(ws + offB);
  float* bias        = (float*)(ws + offBias);
  float* partB       = (float*)(ws + offPartB);
  float* part        = (float*)(ws + offPart);

  k_basis<<<2048, 256, 0, stream>>>(x, A);
  k_coef<<<dim3(32, 32), 256, 0, stream>>>(coeffs, Bt, partB);
  k_bias2<<<4, 256, 0, stream>>>(partB, bias);

  if (ws_size >= needSplit) {
    k_gemm8<true><<<dim3(O_DIM / 256, M_DIM / 256, SPLITS), 512, 0, stream>>>(A, Bt, bias, part);
    k_reduce<<<(M_DIM * O_DIM) / (256 * 4), 256, 0, stream>>>(part, bias, out);
  } else {
    k_gemm8<false><<<dim3(O_DIM / 256, M_DIM / 256, 1), 512, 0, stream>>>(A, Bt, bias, out);
  }
}

// Round 5
// 88.766 us; speedup vs baseline: 3.2008x; 1.0771x over previous
//
#include <hip/hip_runtime.h>
#include <stdint.h>

#define M_DIM 4096
#define I_DIM 1024
#define O_DIM 1024
#define KB 6
#define K_DIM (I_DIM * KB)   // 6144
#define SPLITS 4

typedef __attribute__((ext_vector_type(8))) short short8;
typedef __attribute__((ext_vector_type(4))) float f32x4;
typedef __attribute__((ext_vector_type(4))) unsigned int u32x4;
typedef __attribute__((ext_vector_type(4))) float hfloat4;
typedef __attribute__((ext_vector_type(8))) _Float16 h16x8;

__device__ __forceinline__ unsigned short f2bf(float f) {
  union { float f; unsigned int u; } v; v.f = f;
  unsigned int u = v.u;
  unsigned int r = (u + 0x7FFFu + ((u >> 16) & 1u)) >> 16;
  return (unsigned short)r;
}

// ---- Kernel 1 (fat): blocks [0,2048): basis planes -> bf16 A[4096][6144]
//                      blocks [2048,3072): coeffs -> bf16 Bt[1024][6144] + bias partials
__global__ __launch_bounds__(256) void k_prep(const float* __restrict__ x,
                                              const float* __restrict__ C,
                                              unsigned short* __restrict__ A,
                                              unsigned short* __restrict__ Bt,
                                              float* __restrict__ partB) {
  const int bid = blockIdx.x;
  if (bid < 2048) {
    // ---------------- basis ----------------
    int t = bid * 256 + threadIdx.x;
    long e0 = (long)t * 8;
    const hfloat4* xp = (const hfloat4*)(x + e0);
    hfloat4 v0 = xp[0], v1 = xp[1];
    float xv[8];
    xv[0]=v0[0]; xv[1]=v0[1]; xv[2]=v0[2]; xv[3]=v0[3];
    xv[4]=v1[0]; xv[5]=v1[1]; xv[6]=v1[2]; xv[7]=v1[3];
    unsigned short outv[48];
#pragma unroll
    for (int e = 0; e < 8; ++e) {
      float s  = 1.0f / (1.0f + __expf(-xv[e]));
      float b2 = s, b3 = s, b4 = s * s;
      float b5 = fmaf(s, b4, b3 + b2 + 1.0f);
      float b6 = fmaf(s, b5, b4 + b3 + b2 + 1.0f);
      float b7 = fmaf(s, b6, b5 + b4 + b3 + b2);
      float b8 = fmaf(s, b7, b6 + b5 + b4 + b3);
      outv[e*6+0] = f2bf(s);
      outv[e*6+1] = f2bf(b4);
      outv[e*6+2] = f2bf(b5);
      outv[e*6+3] = f2bf(b6);
      outv[e*6+4] = f2bf(b7);
      outv[e*6+5] = f2bf(b8);
    }
    u32x4* dst = (u32x4*)(A + e0 * KB);
    const u32x4* srcv = (const u32x4*)outv;
#pragma unroll
    for (int q = 0; q < 6; ++q) dst[q] = srcv[q];
  } else {
    // ---------------- coef repack + bias partial ----------------
    __shared__ unsigned short tile[32 * 192];
    __shared__ float bred[256];
    int b = bid - 2048;
    int i0 = (b & 31) * 32, o0 = (b >> 5) * 32;
    int t = threadIdx.x;
    int ol = t & 31, ig = t >> 5;
    float bsum = 0.f;
#pragma unroll
    for (int r = 0; r < 4; ++r) {
      int il = ig + r * 8;
      const float* p = C + (size_t)(i0 + il) * (O_DIM * 9) + (size_t)(o0 + ol) * 9;
      float c1 = p[1];
      float c2 = p[2], c3 = p[3], c4 = p[4], c5 = p[5], c6 = p[6], c7 = p[7], c8 = p[8];
      bsum += c1;
      unsigned short* q = &tile[ol * 192 + il * 6];
      q[0] = f2bf(c2 + c3);
      q[1] = f2bf(c4);
      q[2] = f2bf(c5);
      q[3] = f2bf(c6);
      q[4] = f2bf(c7);
      q[5] = f2bf(c8);
    }
    bred[t] = bsum;
    __syncthreads();
    if (t < 32) {
      float s = 0.f;
#pragma unroll
      for (int g = 0; g < 8; ++g) s += bred[g * 32 + t];
      partB[(size_t)(b & 31) * O_DIM + o0 + t] = s;
    }
    const u32x4* lsrc = (const u32x4*)tile;
#pragma unroll
    for (int r = 0; r < 3; ++r) {
      int c = t + r * 256;
      int row = c / 24, off = c % 24;
      u32x4* gdst = (u32x4*)(Bt + (size_t)(o0 + row) * K_DIM + (size_t)i0 * 6 + off * 8);
      *gdst = lsrc[c];
    }
  }
}

// ---------------- Kernel 2b: final bias reduce (32 partials) -----------------
__global__ __launch_bounds__(256) void k_bias2(const float* __restrict__ partB,
                                               float* __restrict__ bias) {
  int o = blockIdx.x * 256 + threadIdx.x;     // 4 blocks
  float s = 0.f;
#pragma unroll
  for (int ib = 0; ib < 32; ++ib) s += partB[(size_t)ib * O_DIM + o];
  bias[o] = s;
}

// ---------------- Kernel 3: 256x256 8-phase bf16 GEMM (T2+T3+T4+T5) ----------
// 512 thr = 8 waves (2M x 4N); per-wave C = 128x64. BK=64, LDS dbuf 128KB.
// 1 barrier/phase (WAR carried by phase p+1 barrier), XCD panel grouping.
// SPLIT epilogue writes f16 partials (halves partial traffic).
#define SBAR __builtin_amdgcn_sched_barrier(0)

template<bool SPLIT>
__global__ __launch_bounds__(512, 2) void k_gemm8(const unsigned short* __restrict__ A,
                                                  const unsigned short* __restrict__ B,
                                                  const float* __restrict__ bias,
                                                  void* __restrict__ dst) {
  constexpr int CK = SPLIT ? (K_DIM / SPLITS) : K_DIM;   // 1536 / 6144
  constexpr int NT = CK / 64;                            // 24 / 96
  constexpr int PPX = SPLIT ? 8 : 2;                     // (y,z) panels per XCD
  __shared__ char lds[131072];   // [2 buf][A 32KB | B 32KB]
  const int tid = threadIdx.x;
  const int lane = tid & 63, wid = tid >> 6;
  const int wm = wid >> 2, wn = wid & 3;
  const int l15 = lane & 15, lk = lane >> 4, l7 = lane & 7;
  // XCD-grouped bijective remap: 4 n-blocks of one (ym,zk) panel -> same XCD
  const int flat = blockIdx.x + (blockIdx.y << 2) + (blockIdx.z << 6);
  const int xcd = flat & 7, slot = flat >> 3;
  const int panel = xcd * PPX + (slot >> 2);
  const int xn = slot & 3;
  const int ym = panel & 15, zk = panel >> 4;
  const int m0 = ym * 256, n0 = xn * 256;
  const size_t kb = (size_t)zk * CK;
  // staging: thread tid covers LDS rows tid>>3 (+64), chunk slot tid&7;
  // pre-swizzled global chunk = slot ^ (row&7)
  const int srow = tid >> 3;
  const int cg8 = (((tid & 7) ^ ((tid >> 3) & 7)) * 8);  // ushort offset
  // ds_read swizzled chunk offsets (row&7 == lane&7 for all frags)
  const int cx0 = (lk ^ l7) * 16;
  const int cx1 = ((4 + lk) ^ l7) * 16;
  const int arow = wm * 128 + l15;
  const int brow = wn * 64 + l15;

  auto gload = [&](const unsigned short* s, int ldsoff) {
    __builtin_amdgcn_global_load_lds((const __attribute__((address_space(1))) void*)s,
        (__attribute__((address_space(3))) void*)(lds + ldsoff), 16, 0, 0);
  };
  auto stageA = [&](int buf, int h, int kt2) {
    const unsigned short* s = A + (size_t)(m0 + h * 128 + srow) * K_DIM + kb + (size_t)kt2 * 64 + cg8;
    int d = buf * 65536 + h * 16384 + tid * 16;
    gload(s, d);
    gload(s + (size_t)64 * K_DIM, d + 8192);
  };
  auto stageB = [&](int buf, int h, int kt2) {
    const unsigned short* s = B + (size_t)(n0 + h * 128 + srow) * K_DIM + kb + (size_t)kt2 * 64 + cg8;
    int d = buf * 65536 + 32768 + h * 16384 + tid * 16;
    gload(s, d);
    gload(s + (size_t)64 * K_DIM, d + 8192);
  };

  short8 af[4][2], bf0[2][2], bf1[2][2];
  f32x4 acc[8][4];
#pragma unroll
  for (int i = 0; i < 8; ++i)
#pragma unroll
    for (int n = 0; n < 4; ++n)
#pragma unroll
      for (int j = 0; j < 4; ++j) acc[i][n][j] = 0.f;

  auto loadA = [&](int buf, int h) {
#pragma unroll
    for (int mm = 0; mm < 4; ++mm) {
      int rb = buf * 65536 + (arow + h * 64 + mm * 16) * 128;
      af[mm][0] = *(const short8*)(lds + rb + cx0);
      af[mm][1] = *(const short8*)(lds + rb + cx1);
    }
  };
  auto loadB = [&](int buf, int g, short8 (&bfx)[2][2]) {
#pragma unroll
    for (int nn = 0; nn < 2; ++nn) {
      int rb = buf * 65536 + 32768 + (brow + g * 32 + nn * 16) * 128;
      bfx[nn][0] = *(const short8*)(lds + rb + cx0);
      bfx[nn][1] = *(const short8*)(lds + rb + cx1);
    }
  };
  auto quad = [&](int h, int g, short8 (&bfx)[2][2]) {
#pragma unroll
    for (int mm = 0; mm < 4; ++mm)
#pragma unroll
      for (int nn = 0; nn < 2; ++nn)
#pragma unroll
        for (int kc = 0; kc < 2; ++kc)
          acc[h * 4 + mm][g * 2 + nn] =
              __builtin_amdgcn_mfma_f32_16x16x32_bf16(af[mm][kc], bfx[nn][kc],
                                                      acc[h * 4 + mm][g * 2 + nn], 0, 0, 0);
  };
  auto sync1 = [&]() {   // single barrier per phase, then drain ds_reads
    SBAR; __builtin_amdgcn_s_barrier();
    asm volatile("s_waitcnt lgkmcnt(0)" ::: "memory"); SBAR;
    __builtin_amdgcn_s_setprio(1);
  };
  auto endp = [&]() {    // NO barrier: next phase's ds_reads overlap others' MFMA
    __builtin_amdgcn_s_setprio(0); SBAR;
  };

  // prologue: tile0 fully + tile1 B-halves; keep tile1.B in flight (vmcnt 4)
  stageA(0, 0, 0); stageA(0, 1, 0); stageB(0, 0, 0); stageB(0, 1, 0);
  stageB(1, 0, 1); stageB(1, 1, 1);
  asm volatile("s_waitcnt vmcnt(4)" ::: "memory"); SBAR;
  __builtin_amdgcn_s_barrier(); SBAR;

#pragma unroll 1
  for (int kt = 0; kt < NT; ++kt) {
    const int buf = kt & 1, nb = buf ^ 1;
    // ph0: read A(h0)+B(g0); stage (t+1).A1
    loadA(buf, 0); loadB(buf, 0, bf0);
    if (kt + 1 < NT) stageA(nb, 1, kt + 1);
    sync1(); quad(0, 0, bf0); endp();
    // ph1: read B(g1); stage (t+1).A0
    loadB(buf, 1, bf1);
    if (kt + 1 < NT) stageA(nb, 0, kt + 1);
    sync1(); quad(0, 1, bf1); endp();
    // ph2: read A(h1); stage (t+2).B0 (B0 last read ph0; ph1 barrier orders)
    loadA(buf, 1);
    if (kt + 2 < NT) stageB(buf, 0, kt + 2);
    sync1(); quad(1, 1, bf1); endp();
    // ph3: stage (t+2).B1 (B1 last read ph1; ph2 barrier orders)
    if (kt + 2 < NT) stageB(buf, 1, kt + 2);
    sync1(); quad(1, 0, bf0); endp();
    // tile boundary: counted vmcnt -> next buf valid after barrier
    if (kt + 1 < NT) {
      if (kt + 2 < NT) asm volatile("s_waitcnt vmcnt(4)" ::: "memory");
      else             asm volatile("s_waitcnt vmcnt(0)" ::: "memory");
      SBAR;
      __builtin_amdgcn_s_barrier(); SBAR;
    }
  }

  // epilogue: C/D layout col = lane&15, row = (lane>>4)*4 + j
  if (SPLIT) {
    _Float16* base = (_Float16*)dst + (size_t)zk * ((size_t)M_DIM * O_DIM);
#pragma unroll
    for (int mi = 0; mi < 8; ++mi) {
      int r0 = m0 + wm * 128 + mi * 16 + (lk << 2);
#pragma unroll
      for (int ni = 0; ni < 4; ++ni) {
        int col = n0 + wn * 64 + ni * 16 + l15;
#pragma unroll
        for (int j = 0; j < 4; ++j)
          base[(size_t)(r0 + j) * O_DIM + col] = (_Float16)acc[mi][ni][j];
      }
    }
  } else {
    float* base = (float*)dst;
#pragma unroll
    for (int mi = 0; mi < 8; ++mi) {
      int r0 = m0 + wm * 128 + mi * 16 + (lk << 2);
#pragma unroll
      for (int ni = 0; ni < 4; ++ni) {
        int col = n0 + wn * 64 + ni * 16 + l15;
        float bv = bias[col];
#pragma unroll
        for (int j = 0; j < 4; ++j)
          base[(size_t)(r0 + j) * O_DIM + col] = acc[mi][ni][j] + bv;
      }
    }
  }
}

// ---------------- Kernel 4: reduce f16 split-K partials + bias ---------------
__global__ __launch_bounds__(256) void k_reduce(const _Float16* __restrict__ part,
                                                const float* __restrict__ bias,
                                                float* __restrict__ out) {
  size_t t = (size_t)blockIdx.x * 256 + threadIdx.x;   // 2048 blocks, 8 out/thread
  size_t idx = t * 8;
  const size_t P = (size_t)M_DIM * O_DIM;
  h16x8 s0 = *(const h16x8*)(part + idx);
  h16x8 s1 = *(const h16x8*)(part + P + idx);
  h16x8 s2 = *(const h16x8*)(part + 2 * P + idx);
  h16x8 s3 = *(const h16x8*)(part + 3 * P + idx);
  size_t bo = idx & (O_DIM - 1);
  f32x4 b0 = *(const f32x4*)(bias + bo);
  f32x4 b1 = *(const f32x4*)(bias + bo + 4);
  f32x4 r0, r1;
#pragma unroll
  for (int j = 0; j < 4; ++j) {
    r0[j] = (((float)s0[j] + (float)s1[j]) + ((float)s2[j] + (float)s3[j])) + b0[j];
    r1[j] = (((float)s0[j+4] + (float)s1[j+4]) + ((float)s2[j+4] + (float)s3[j+4])) + b1[j];
  }
  *(f32x4*)(out + idx) = r0;
  *(f32x4*)(out + idx + 4) = r1;
}

extern "C" void kernel_launch(void* const* d_in, const int* in_sizes, int n_in,
                              void* d_out, int out_size, void* d_ws, size_t ws_size,
                              hipStream_t stream) {
  const float* x      = (const float*)d_in[0];
  const float* coeffs = (const float*)d_in[1];
  float* out = (float*)d_out;
  char* ws = (char*)d_ws;
  const size_t offA     = 0;
  const size_t offB     = 50331648;                // A: 4096*6144*2
  const size_t offBias  = offB + 12582912;         // Bt: 1024*6144*2
  const size_t offPartB = offBias + 4096;          // bias: 1024*4
  const size_t offPart  = offPartB + 131072;       // partB: 32*1024*4
  const size_t needSplit = offPart + (size_t)SPLITS * M_DIM * O_DIM * 2;  // f16 partials

  unsigned short* A  = (unsigned short*)(ws + offA);
  unsigned short* Bt = (unsigned short*)(ws + offB);
  float* bias        = (float*)(ws + offBias);
  float* partB       = (float*)(ws + offPartB);
  _Float16* part     = (_Float16*)(ws + offPart);

  k_prep<<<3072, 256, 0, stream>>>(x, coeffs, A, Bt, partB);
  k_bias2<<<4, 256, 0, stream>>>(partB, bias);

  if (ws_size >= needSplit) {
    k_gemm8<true><<<dim3(O_DIM / 256, M_DIM / 256, SPLITS), 512, 0, stream>>>(A, Bt, bias, (void*)part);
    k_reduce<<<(M_DIM * O_DIM) / (256 * 8), 256, 0, stream>>>(part, bias, out);
  } else {
    k_gemm8<false><<<dim3(O_DIM / 256, M_DIM / 256, 1), 512, 0, stream>>>(A, Bt, bias, (void*)out);
  }
}

// Round 6
// 88.228 us; speedup vs baseline: 3.2204x; 1.0061x over previous
//
#include <hip/hip_runtime.h>
#include <stdint.h>

#define M_DIM 4096
#define I_DIM 1024
#define O_DIM 1024
#define KB 6
#define K_DIM (I_DIM * KB)   // 6144
#define SPLITS 4

typedef __attribute__((ext_vector_type(8))) short short8;
typedef __attribute__((ext_vector_type(4))) float f32x4;
typedef __attribute__((ext_vector_type(4))) unsigned int u32x4;
typedef __attribute__((ext_vector_type(4))) float hfloat4;
typedef __attribute__((ext_vector_type(8))) _Float16 h16x8;

__device__ __forceinline__ unsigned short f2bf(float f) {
  union { float f; unsigned int u; } v; v.f = f;
  unsigned int u = v.u;
  unsigned int r = (u + 0x7FFFu + ((u >> 16) & 1u)) >> 16;
  return (unsigned short)r;
}

// ---- Kernel 1 (fat): blocks [0,2048): basis planes -> bf16 A[4096][6144]
//                      blocks [2048,3072): coeffs -> bf16 Bt[1024][6144] + bias partials
__global__ __launch_bounds__(256) void k_prep(const float* __restrict__ x,
                                              const float* __restrict__ C,
                                              unsigned short* __restrict__ A,
                                              unsigned short* __restrict__ Bt,
                                              float* __restrict__ partB) {
  const int bid = blockIdx.x;
  if (bid < 2048) {
    // ---------------- basis ----------------
    int t = bid * 256 + threadIdx.x;
    long e0 = (long)t * 8;
    const hfloat4* xp = (const hfloat4*)(x + e0);
    hfloat4 v0 = xp[0], v1 = xp[1];
    float xv[8];
    xv[0]=v0[0]; xv[1]=v0[1]; xv[2]=v0[2]; xv[3]=v0[3];
    xv[4]=v1[0]; xv[5]=v1[1]; xv[6]=v1[2]; xv[7]=v1[3];
    unsigned short outv[48];
#pragma unroll
    for (int e = 0; e < 8; ++e) {
      float s  = 1.0f / (1.0f + __expf(-xv[e]));
      float b2 = s, b3 = s, b4 = s * s;
      float b5 = fmaf(s, b4, b3 + b2 + 1.0f);
      float b6 = fmaf(s, b5, b4 + b3 + b2 + 1.0f);
      float b7 = fmaf(s, b6, b5 + b4 + b3 + b2);
      float b8 = fmaf(s, b7, b6 + b5 + b4 + b3);
      outv[e*6+0] = f2bf(s);
      outv[e*6+1] = f2bf(b4);
      outv[e*6+2] = f2bf(b5);
      outv[e*6+3] = f2bf(b6);
      outv[e*6+4] = f2bf(b7);
      outv[e*6+5] = f2bf(b8);
    }
    u32x4* dst = (u32x4*)(A + e0 * KB);
    const u32x4* srcv = (const u32x4*)outv;
#pragma unroll
    for (int q = 0; q < 6; ++q) dst[q] = srcv[q];
  } else {
    // ---------------- coef repack + bias partial ----------------
    __shared__ unsigned short tile[32 * 192];
    __shared__ float bred[256];
    int b = bid - 2048;
    int i0 = (b & 31) * 32, o0 = (b >> 5) * 32;
    int t = threadIdx.x;
    int ol = t & 31, ig = t >> 5;
    float bsum = 0.f;
#pragma unroll
    for (int r = 0; r < 4; ++r) {
      int il = ig + r * 8;
      const float* p = C + (size_t)(i0 + il) * (O_DIM * 9) + (size_t)(o0 + ol) * 9;
      float c1 = p[1];
      float c2 = p[2], c3 = p[3], c4 = p[4], c5 = p[5], c6 = p[6], c7 = p[7], c8 = p[8];
      bsum += c1;
      unsigned short* q = &tile[ol * 192 + il * 6];
      q[0] = f2bf(c2 + c3);
      q[1] = f2bf(c4);
      q[2] = f2bf(c5);
      q[3] = f2bf(c6);
      q[4] = f2bf(c7);
      q[5] = f2bf(c8);
    }
    bred[t] = bsum;
    __syncthreads();
    if (t < 32) {
      float s = 0.f;
#pragma unroll
      for (int g = 0; g < 8; ++g) s += bred[g * 32 + t];
      partB[(size_t)(b & 31) * O_DIM + o0 + t] = s;
    }
    const u32x4* lsrc = (const u32x4*)tile;
#pragma unroll
    for (int r = 0; r < 3; ++r) {
      int c = t + r * 256;
      int row = c / 24, off = c % 24;
      u32x4* gdst = (u32x4*)(Bt + (size_t)(o0 + row) * K_DIM + (size_t)i0 * 6 + off * 8);
      *gdst = lsrc[c];
    }
  }
}

// ---------------- Kernel 2b: final bias reduce (32 partials) -----------------
__global__ __launch_bounds__(256) void k_bias2(const float* __restrict__ partB,
                                               float* __restrict__ bias) {
  int o = blockIdx.x * 256 + threadIdx.x;     // 4 blocks
  float s = 0.f;
#pragma unroll
  for (int ib = 0; ib < 32; ++ib) s += partB[(size_t)ib * O_DIM + o];
  bias[o] = s;
}

// ---------------- Kernel 3: 256x256 bf16 GEMM, 1-barrier/tile pipeline -------
// 512 thr = 8 waves (2M x 4N); per-wave C = 128x64. BK=64, LDS dbuf 128KB.
// Per tile: issue 8 gload_lds (tile kt+1 -> nb) + 24 ds_read (tile kt), then
// 4 MFMA quads; compiler inserts counted lgkmcnt. One vmcnt(0)+barrier/tile.
// WAR safe: nb's reads (tile kt-1) retired before the kt-1->kt barrier.
#define SBAR __builtin_amdgcn_sched_barrier(0)

template<bool SPLIT>
__global__ __launch_bounds__(512, 2) void k_gemm8(const unsigned short* __restrict__ A,
                                                  const unsigned short* __restrict__ B,
                                                  const float* __restrict__ bias,
                                                  void* __restrict__ dst) {
  constexpr int CK = SPLIT ? (K_DIM / SPLITS) : K_DIM;   // 1536 / 6144
  constexpr int NT = CK / 64;                            // 24 / 96
  constexpr int PPX = SPLIT ? 8 : 2;                     // (y,z) panels per XCD
  __shared__ char lds[131072];   // [2 buf][A 32KB | B 32KB]
  const int tid = threadIdx.x;
  const int lane = tid & 63, wid = tid >> 6;
  const int wm = wid >> 2, wn = wid & 3;
  const int l15 = lane & 15, lk = lane >> 4, l7 = lane & 7;
  // XCD-grouped bijective remap: 4 n-blocks of one (ym,zk) panel -> same XCD
  const int flat = blockIdx.x + (blockIdx.y << 2) + (blockIdx.z << 6);
  const int xcd = flat & 7, slot = flat >> 3;
  const int panel = xcd * PPX + (slot >> 2);
  const int xn = slot & 3;
  const int ym = panel & 15, zk = panel >> 4;
  const int m0 = ym * 256, n0 = xn * 256;
  const size_t kb = (size_t)zk * CK;
  // staging: thread tid covers LDS rows tid>>3 (+64), chunk slot tid&7;
  // pre-swizzled global chunk = slot ^ (row&7)
  const int srow = tid >> 3;
  const int cg8 = (((tid & 7) ^ ((tid >> 3) & 7)) * 8);  // ushort offset
  // ds_read swizzled chunk offsets (row&7 == lane&7 for all frags)
  const int cx0 = (lk ^ l7) * 16;
  const int cx1 = ((4 + lk) ^ l7) * 16;
  const int arow = wm * 128 + l15;
  const int brow = wn * 64 + l15;

  auto gload = [&](const unsigned short* s, int ldsoff) {
    __builtin_amdgcn_global_load_lds((const __attribute__((address_space(1))) void*)s,
        (__attribute__((address_space(3))) void*)(lds + ldsoff), 16, 0, 0);
  };
  auto stageA = [&](int buf, int h, int kt2) {
    const unsigned short* s = A + (size_t)(m0 + h * 128 + srow) * K_DIM + kb + (size_t)kt2 * 64 + cg8;
    int d = buf * 65536 + h * 16384 + tid * 16;
    gload(s, d);
    gload(s + (size_t)64 * K_DIM, d + 8192);
  };
  auto stageB = [&](int buf, int h, int kt2) {
    const unsigned short* s = B + (size_t)(n0 + h * 128 + srow) * K_DIM + kb + (size_t)kt2 * 64 + cg8;
    int d = buf * 65536 + 32768 + h * 16384 + tid * 16;
    gload(s, d);
    gload(s + (size_t)64 * K_DIM, d + 8192);
  };

  short8 af0[4][2], af1[4][2], bf0[2][2], bf1[2][2];
  f32x4 acc[8][4];
#pragma unroll
  for (int i = 0; i < 8; ++i)
#pragma unroll
    for (int n = 0; n < 4; ++n)
#pragma unroll
      for (int j = 0; j < 4; ++j) acc[i][n][j] = 0.f;

  auto loadA = [&](int buf, int h, short8 (&afx)[4][2]) {
#pragma unroll
    for (int mm = 0; mm < 4; ++mm) {
      int rb = buf * 65536 + (arow + h * 64 + mm * 16) * 128;
      afx[mm][0] = *(const short8*)(lds + rb + cx0);
      afx[mm][1] = *(const short8*)(lds + rb + cx1);
    }
  };
  auto loadB = [&](int buf, int g, short8 (&bfx)[2][2]) {
#pragma unroll
    for (int nn = 0; nn < 2; ++nn) {
      int rb = buf * 65536 + 32768 + (brow + g * 32 + nn * 16) * 128;
      bfx[nn][0] = *(const short8*)(lds + rb + cx0);
      bfx[nn][1] = *(const short8*)(lds + rb + cx1);
    }
  };
  auto quad = [&](short8 (&afx)[4][2], int h, int g, short8 (&bfx)[2][2]) {
#pragma unroll
    for (int mm = 0; mm < 4; ++mm)
#pragma unroll
      for (int nn = 0; nn < 2; ++nn)
#pragma unroll
        for (int kc = 0; kc < 2; ++kc)
          acc[h * 4 + mm][g * 2 + nn] =
              __builtin_amdgcn_mfma_f32_16x16x32_bf16(afx[mm][kc], bfx[nn][kc],
                                                      acc[h * 4 + mm][g * 2 + nn], 0, 0, 0);
  };

  // prologue: stage tile0 into buf0, drain, barrier
  stageA(0, 0, 0); stageA(0, 1, 0); stageB(0, 0, 0); stageB(0, 1, 0);
  asm volatile("s_waitcnt vmcnt(0)" ::: "memory"); SBAR;
  __builtin_amdgcn_s_barrier(); SBAR;

#pragma unroll 1
  for (int kt = 0; kt < NT; ++kt) {
    const int buf = kt & 1, nb = buf ^ 1;
    // issue next tile's staging first (hits HBM/L2 early; lands well before boundary)
    if (kt + 1 < NT) {
      stageA(nb, 0, kt + 1); stageA(nb, 1, kt + 1);
      stageB(nb, 0, kt + 1); stageB(nb, 1, kt + 1);
    }
    // issue all 24 ds_reads of current tile; compiler inserts counted lgkmcnt
    loadA(buf, 0, af0); loadB(buf, 0, bf0);
    loadB(buf, 1, bf1); loadA(buf, 1, af1);
    __builtin_amdgcn_s_setprio(1);
    quad(af0, 0, 0, bf0); quad(af0, 0, 1, bf1);
    quad(af1, 1, 1, bf1); quad(af1, 1, 0, bf0);
    __builtin_amdgcn_s_setprio(0); SBAR;
    // tile boundary: single drain + single barrier
    if (kt + 1 < NT) {
      asm volatile("s_waitcnt vmcnt(0)" ::: "memory"); SBAR;
      __builtin_amdgcn_s_barrier(); SBAR;
    }
  }

  // epilogue: C/D layout col = lane&15, row = (lane>>4)*4 + j
  if (SPLIT) {
    _Float16* base = (_Float16*)dst + (size_t)zk * ((size_t)M_DIM * O_DIM);
#pragma unroll
    for (int mi = 0; mi < 8; ++mi) {
      int r0 = m0 + wm * 128 + mi * 16 + (lk << 2);
#pragma unroll
      for (int ni = 0; ni < 4; ++ni) {
        int col = n0 + wn * 64 + ni * 16 + l15;
#pragma unroll
        for (int j = 0; j < 4; ++j)
          base[(size_t)(r0 + j) * O_DIM + col] = (_Float16)acc[mi][ni][j];
      }
    }
  } else {
    float* base = (float*)dst;
#pragma unroll
    for (int mi = 0; mi < 8; ++mi) {
      int r0 = m0 + wm * 128 + mi * 16 + (lk << 2);
#pragma unroll
      for (int ni = 0; ni < 4; ++ni) {
        int col = n0 + wn * 64 + ni * 16 + l15;
        float bv = bias[col];
#pragma unroll
        for (int j = 0; j < 4; ++j)
          base[(size_t)(r0 + j) * O_DIM + col] = acc[mi][ni][j] + bv;
      }
    }
  }
}

// ---------------- Kernel 4: reduce f16 split-K partials + bias ---------------
__global__ __launch_bounds__(256) void k_reduce(const _Float16* __restrict__ part,
                                                const float* __restrict__ bias,
                                                float* __restrict__ out) {
  size_t t = (size_t)blockIdx.x * 256 + threadIdx.x;   // 2048 blocks, 8 out/thread
  size_t idx = t * 8;
  const size_t P = (size_t)M_DIM * O_DIM;
  h16x8 s0 = *(const h16x8*)(part + idx);
  h16x8 s1 = *(const h16x8*)(part + P + idx);
  h16x8 s2 = *(const h16x8*)(part + 2 * P + idx);
  h16x8 s3 = *(const h16x8*)(part + 3 * P + idx);
  size_t bo = idx & (O_DIM - 1);
  f32x4 b0 = *(const f32x4*)(bias + bo);
  f32x4 b1 = *(const f32x4*)(bias + bo + 4);
  f32x4 r0, r1;
#pragma unroll
  for (int j = 0; j < 4; ++j) {
    r0[j] = (((float)s0[j] + (float)s1[j]) + ((float)s2[j] + (float)s3[j])) + b0[j];
    r1[j] = (((float)s0[j+4] + (float)s1[j+4]) + ((float)s2[j+4] + (float)s3[j+4])) + b1[j];
  }
  *(f32x4*)(out + idx) = r0;
  *(f32x4*)(out + idx + 4) = r1;
}

extern "C" void kernel_launch(void* const* d_in, const int* in_sizes, int n_in,
                              void* d_out, int out_size, void* d_ws, size_t ws_size,
                              hipStream_t stream) {
  const float* x      = (const float*)d_in[0];
  const float* coeffs = (const float*)d_in[1];
  float* out = (float*)d_out;
  char* ws = (char*)d_ws;
  const size_t offA     = 0;
  const size_t offB     = 50331648;                // A: 4096*6144*2
  const size_t offBias  = offB + 12582912;         // Bt: 1024*6144*2
  const size_t offPartB = offBias + 4096;          // bias: 1024*4
  const size_t offPart  = offPartB + 131072;       // partB: 32*1024*4
  const size_t needSplit = offPart + (size_t)SPLITS * M_DIM * O_DIM * 2;  // f16 partials

  unsigned short* A  = (unsigned short*)(ws + offA);
  unsigned short* Bt = (unsigned short*)(ws + offB);
  float* bias        = (float*)(ws + offBias);
  float* partB       = (float*)(ws + offPartB);
  _Float16* part     = (_Float16*)(ws + offPart);

  k_prep<<<3072, 256, 0, stream>>>(x, coeffs, A, Bt, partB);
  k_bias2<<<4, 256, 0, stream>>>(partB, bias);

  if (ws_size >= needSplit) {
    k_gemm8<true><<<dim3(O_DIM / 256, M_DIM / 256, SPLITS), 512, 0, stream>>>(A, Bt, bias, (void*)part);
    k_reduce<<<(M_DIM * O_DIM) / (256 * 8), 256, 0, stream>>>(part, bias, out);
  } else {
    k_gemm8<false><<<dim3(O_DIM / 256, M_DIM / 256, 1), 512, 0, stream>>>(A, Bt, bias, (void*)out);
  }
}

// Round 7
// 86.936 us; speedup vs baseline: 3.2682x; 1.0149x over previous
//
#include <hip/hip_runtime.h>
#include <stdint.h>

#define M_DIM 4096
#define I_DIM 1024
#define O_DIM 1024
#define KB 6
#define K_DIM (I_DIM * KB)   // 6144
#define SPLITS 4

typedef __attribute__((ext_vector_type(8))) short short8;
typedef __attribute__((ext_vector_type(4))) float f32x4;
typedef __attribute__((ext_vector_type(4))) unsigned int u32x4;
typedef __attribute__((ext_vector_type(4))) float hfloat4;
typedef __attribute__((ext_vector_type(8))) _Float16 h16x8;

__device__ __forceinline__ unsigned short f2bf(float f) {
  union { float f; unsigned int u; } v; v.f = f;
  unsigned int u = v.u;
  unsigned int r = (u + 0x7FFFu + ((u >> 16) & 1u)) >> 16;
  return (unsigned short)r;
}

// ---- Kernel 1 (fat): blocks [0,2048): basis planes -> bf16 A[4096][6144]
//                      blocks [2048,3072): coeffs -> bf16 Bt[1024][6144] + bias partials
__global__ __launch_bounds__(256) void k_prep(const float* __restrict__ x,
                                              const float* __restrict__ C,
                                              unsigned short* __restrict__ A,
                                              unsigned short* __restrict__ Bt,
                                              float* __restrict__ partB) {
  const int bid = blockIdx.x;
  if (bid < 2048) {
    int t = bid * 256 + threadIdx.x;
    long e0 = (long)t * 8;
    const hfloat4* xp = (const hfloat4*)(x + e0);
    hfloat4 v0 = xp[0], v1 = xp[1];
    float xv[8];
    xv[0]=v0[0]; xv[1]=v0[1]; xv[2]=v0[2]; xv[3]=v0[3];
    xv[4]=v1[0]; xv[5]=v1[1]; xv[6]=v1[2]; xv[7]=v1[3];
    unsigned short outv[48];
#pragma unroll
    for (int e = 0; e < 8; ++e) {
      float s  = 1.0f / (1.0f + __expf(-xv[e]));
      float b2 = s, b3 = s, b4 = s * s;
      float b5 = fmaf(s, b4, b3 + b2 + 1.0f);
      float b6 = fmaf(s, b5, b4 + b3 + b2 + 1.0f);
      float b7 = fmaf(s, b6, b5 + b4 + b3 + b2);
      float b8 = fmaf(s, b7, b6 + b5 + b4 + b3);
      outv[e*6+0] = f2bf(s);
      outv[e*6+1] = f2bf(b4);
      outv[e*6+2] = f2bf(b5);
      outv[e*6+3] = f2bf(b6);
      outv[e*6+4] = f2bf(b7);
      outv[e*6+5] = f2bf(b8);
    }
    u32x4* dst = (u32x4*)(A + e0 * KB);
    const u32x4* srcv = (const u32x4*)outv;
#pragma unroll
    for (int q = 0; q < 6; ++q) dst[q] = srcv[q];
  } else {
    __shared__ unsigned short tile[32 * 192];
    __shared__ float bred[256];
    int b = bid - 2048;
    int i0 = (b & 31) * 32, o0 = (b >> 5) * 32;
    int t = threadIdx.x;
    int ol = t & 31, ig = t >> 5;
    float bsum = 0.f;
#pragma unroll
    for (int r = 0; r < 4; ++r) {
      int il = ig + r * 8;
      const float* p = C + (size_t)(i0 + il) * (O_DIM * 9) + (size_t)(o0 + ol) * 9;
      float c1 = p[1];
      float c2 = p[2], c3 = p[3], c4 = p[4], c5 = p[5], c6 = p[6], c7 = p[7], c8 = p[8];
      bsum += c1;
      unsigned short* q = &tile[ol * 192 + il * 6];
      q[0] = f2bf(c2 + c3);
      q[1] = f2bf(c4);
      q[2] = f2bf(c5);
      q[3] = f2bf(c6);
      q[4] = f2bf(c7);
      q[5] = f2bf(c8);
    }
    bred[t] = bsum;
    __syncthreads();
    if (t < 32) {
      float s = 0.f;
#pragma unroll
      for (int g = 0; g < 8; ++g) s += bred[g * 32 + t];
      partB[(size_t)(b & 31) * O_DIM + o0 + t] = s;
    }
    const u32x4* lsrc = (const u32x4*)tile;
#pragma unroll
    for (int r = 0; r < 3; ++r) {
      int c = t + r * 256;
      int row = c / 24, off = c % 24;
      u32x4* gdst = (u32x4*)(Bt + (size_t)(o0 + row) * K_DIM + (size_t)i0 * 6 + off * 8);
      *gdst = lsrc[c];
    }
  }
}

// ---------------- Kernel 2b: final bias reduce (32 partials) -----------------
__global__ __launch_bounds__(256) void k_bias2(const float* __restrict__ partB,
                                               float* __restrict__ bias) {
  int o = blockIdx.x * 256 + threadIdx.x;     // 4 blocks
  float s = 0.f;
#pragma unroll
  for (int ib = 0; ib < 32; ++ib) s += partB[(size_t)ib * O_DIM + o];
  bias[o] = s;
}

// ---------------- Kernel 3: 256x256 bf16 GEMM, cross-phase pipeline ----------
// 512 thr = 8 waves (2M x 4N); per-wave C = 128x64. BK=64, LDS dbuf 128KB.
// Fragments split by K-half (kc). Steady state: MFMA(kc0) overlaps kc1 reads;
// MFMA(kc1) overlaps next tile's kc0 reads (issued right after the boundary
// barrier). One vmcnt(0)+lgkm(0)+barrier per tile.
#define SBAR __builtin_amdgcn_sched_barrier(0)

template<bool SPLIT>
__global__ __launch_bounds__(512, 2) void k_gemm8(const unsigned short* __restrict__ A,
                                                  const unsigned short* __restrict__ B,
                                                  const float* __restrict__ bias,
                                                  void* __restrict__ dst) {
  constexpr int CK = SPLIT ? (K_DIM / SPLITS) : K_DIM;   // 1536 / 6144
  constexpr int NT = CK / 64;                            // 24 / 96
  constexpr int PPX = SPLIT ? 8 : 2;                     // (y,z) panels per XCD
  __shared__ char lds[131072];   // [2 buf][A 32KB | B 32KB]
  const int tid = threadIdx.x;
  const int lane = tid & 63, wid = tid >> 6;
  const int wm = wid >> 2, wn = wid & 3;
  const int l15 = lane & 15, lk = lane >> 4, l7 = lane & 7;
  // XCD-grouped bijective remap: 4 n-blocks of one (ym,zk) panel -> same XCD
  const int flat = blockIdx.x + (blockIdx.y << 2) + (blockIdx.z << 6);
  const int xcd = flat & 7, slot = flat >> 3;
  const int panel = xcd * PPX + (slot >> 2);
  const int xn = slot & 3;
  const int ym = panel & 15, zk = panel >> 4;
  const int m0 = ym * 256, n0 = xn * 256;
  const size_t kb = (size_t)zk * CK;
  // staging: thread tid covers LDS rows tid>>3 (+64), chunk slot tid&7;
  // pre-swizzled global chunk = slot ^ (row&7)
  const int srow = tid >> 3;
  const int cg8 = (((tid & 7) ^ ((tid >> 3) & 7)) * 8);  // ushort offset
  // ds_read swizzled chunk offsets (row&7 == lane&7 for all frags)
  const int cx0 = (lk ^ l7) * 16;
  const int cx1 = ((4 + lk) ^ l7) * 16;
  const int arow = wm * 128 + l15;
  const int brow = wn * 64 + l15;

  auto gload = [&](const unsigned short* s, int ldsoff) {
    __builtin_amdgcn_global_load_lds((const __attribute__((address_space(1))) void*)s,
        (__attribute__((address_space(3))) void*)(lds + ldsoff), 16, 0, 0);
  };
  auto stageA = [&](int buf, int h, int kt2) {
    const unsigned short* s = A + (size_t)(m0 + h * 128 + srow) * K_DIM + kb + (size_t)kt2 * 64 + cg8;
    int d = buf * 65536 + h * 16384 + tid * 16;
    gload(s, d);
    gload(s + (size_t)64 * K_DIM, d + 8192);
  };
  auto stageB = [&](int buf, int h, int kt2) {
    const unsigned short* s = B + (size_t)(n0 + h * 128 + srow) * K_DIM + kb + (size_t)kt2 * 64 + cg8;
    int d = buf * 65536 + 32768 + h * 16384 + tid * 16;
    gload(s, d);
    gload(s + (size_t)64 * K_DIM, d + 8192);
  };

  // fragments: one K-half (12 x b128) per set
  short8 a0[8], b0v[4], a1[8], b1v[4];
  f32x4 acc[8][4];
#pragma unroll
  for (int i = 0; i < 8; ++i)
#pragma unroll
    for (int n = 0; n < 4; ++n)
#pragma unroll
      for (int j = 0; j < 4; ++j) acc[i][n][j] = 0.f;

  auto readK = [&](int buf, int cx, short8 (&av)[8], short8 (&bv)[4]) {
#pragma unroll
    for (int mi = 0; mi < 8; ++mi)
      av[mi] = *(const short8*)(lds + buf * 65536 + (arow + mi * 16) * 128 + cx);
#pragma unroll
    for (int ni = 0; ni < 4; ++ni)
      bv[ni] = *(const short8*)(lds + buf * 65536 + 32768 + (brow + ni * 16) * 128 + cx);
  };
  auto quadK = [&](short8 (&av)[8], short8 (&bv)[4]) {
#pragma unroll
    for (int mi = 0; mi < 8; ++mi)
#pragma unroll
      for (int ni = 0; ni < 4; ++ni)
        acc[mi][ni] = __builtin_amdgcn_mfma_f32_16x16x32_bf16(av[mi], bv[ni], acc[mi][ni], 0, 0, 0);
  };

  // prologue: stage tile0 into buf0, drain, barrier, read kc0 frags
  stageA(0, 0, 0); stageA(0, 1, 0); stageB(0, 0, 0); stageB(0, 1, 0);
  asm volatile("s_waitcnt vmcnt(0)" ::: "memory"); SBAR;
  __builtin_amdgcn_s_barrier(); SBAR;
  readK(0, cx0, a0, b0v);

#pragma unroll 1
  for (int kt = 0; kt < NT; ++kt) {
    const int buf = kt & 1, nb = buf ^ 1;
    // stage next tile (8 gload_lds) -- lands before the boundary drain
    if (kt + 1 < NT) {
      stageA(nb, 0, kt + 1); stageA(nb, 1, kt + 1);
      stageB(nb, 0, kt + 1); stageB(nb, 1, kt + 1);
    }
    // issue kc1 reads of current tile, then MFMA kc0 overlapping them
    readK(buf, cx1, a1, b1v);
    __builtin_amdgcn_s_setprio(1);
    quadK(a0, b0v);
    __builtin_amdgcn_s_setprio(0); SBAR;
    // boundary: kc1 reads drained (WAR), staging drained (RAW), one barrier
    asm volatile("s_waitcnt lgkmcnt(0)" ::: "memory"); SBAR;
    if (kt + 1 < NT) {
      asm volatile("s_waitcnt vmcnt(0)" ::: "memory"); SBAR;
      __builtin_amdgcn_s_barrier(); SBAR;
      // issue next tile's kc0 reads, then MFMA kc1 overlapping them
      readK(nb, cx0, a0, b0v);
    }
    __builtin_amdgcn_s_setprio(1);
    quadK(a1, b1v);
    __builtin_amdgcn_s_setprio(0); SBAR;
  }

  // epilogue: C/D layout col = lane&15, row = (lane>>4)*4 + j
  if (SPLIT) {
    _Float16* base = (_Float16*)dst + (size_t)zk * ((size_t)M_DIM * O_DIM);
#pragma unroll
    for (int mi = 0; mi < 8; ++mi) {
      int r0 = m0 + wm * 128 + mi * 16 + (lk << 2);
#pragma unroll
      for (int ni = 0; ni < 4; ++ni) {
        int col = n0 + wn * 64 + ni * 16 + l15;
#pragma unroll
        for (int j = 0; j < 4; ++j)
          base[(size_t)(r0 + j) * O_DIM + col] = (_Float16)acc[mi][ni][j];
      }
    }
  } else {
    float* base = (float*)dst;
#pragma unroll
    for (int mi = 0; mi < 8; ++mi) {
      int r0 = m0 + wm * 128 + mi * 16 + (lk << 2);
#pragma unroll
      for (int ni = 0; ni < 4; ++ni) {
        int col = n0 + wn * 64 + ni * 16 + l15;
        float bv = bias[col];
#pragma unroll
        for (int j = 0; j < 4; ++j)
          base[(size_t)(r0 + j) * O_DIM + col] = acc[mi][ni][j] + bv;
      }
    }
  }
}

// ---------------- Kernel 4: reduce f16 split-K partials + bias ---------------
__global__ __launch_bounds__(256) void k_reduce(const _Float16* __restrict__ part,
                                                const float* __restrict__ bias,
                                                float* __restrict__ out) {
  size_t t = (size_t)blockIdx.x * 256 + threadIdx.x;   // 2048 blocks, 8 out/thread
  size_t idx = t * 8;
  const size_t P = (size_t)M_DIM * O_DIM;
  h16x8 s0 = *(const h16x8*)(part + idx);
  h16x8 s1 = *(const h16x8*)(part + P + idx);
  h16x8 s2 = *(const h16x8*)(part + 2 * P + idx);
  h16x8 s3 = *(const h16x8*)(part + 3 * P + idx);
  size_t bo = idx & (O_DIM - 1);
  f32x4 b0 = *(const f32x4*)(bias + bo);
  f32x4 b1 = *(const f32x4*)(bias + bo + 4);
  f32x4 r0, r1;
#pragma unroll
  for (int j = 0; j < 4; ++j) {
    r0[j] = (((float)s0[j] + (float)s1[j]) + ((float)s2[j] + (float)s3[j])) + b0[j];
    r1[j] = (((float)s0[j+4] + (float)s1[j+4]) + ((float)s2[j+4] + (float)s3[j+4])) + b1[j];
  }
  *(f32x4*)(out + idx) = r0;
  *(f32x4*)(out + idx + 4) = r1;
}

extern "C" void kernel_launch(void* const* d_in, const int* in_sizes, int n_in,
                              void* d_out, int out_size, void* d_ws, size_t ws_size,
                              hipStream_t stream) {
  const float* x      = (const float*)d_in[0];
  const float* coeffs = (const float*)d_in[1];
  float* out = (float*)d_out;
  char* ws = (char*)d_ws;
  const size_t offA     = 0;
  const size_t offB     = 50331648;                // A: 4096*6144*2
  const size_t offBias  = offB + 12582912;         // Bt: 1024*6144*2
  const size_t offPartB = offBias + 4096;          // bias: 1024*4
  const size_t offPart  = offPartB + 131072;       // partB: 32*1024*4
  const size_t needSplit = offPart + (size_t)SPLITS * M_DIM * O_DIM * 2;  // f16 partials

  unsigned short* A  = (unsigned short*)(ws + offA);
  unsigned short* Bt = (unsigned short*)(ws + offB);
  float* bias        = (float*)(ws + offBias);
  float* partB       = (float*)(ws + offPartB);
  _Float16* part     = (_Float16*)(ws + offPart);

  k_prep<<<3072, 256, 0, stream>>>(x, coeffs, A, Bt, partB);
  k_bias2<<<4, 256, 0, stream>>>(partB, bias);

  if (ws_size >= needSplit) {
    k_gemm8<true><<<dim3(O_DIM / 256, M_DIM / 256, SPLITS), 512, 0, stream>>>(A, Bt, bias, (void*)part);
    k_reduce<<<(M_DIM * O_DIM) / (256 * 8), 256, 0, stream>>>(part, bias, out);
  } else {
    k_gemm8<false><<<dim3(O_DIM / 256, M_DIM / 256, 1), 512, 0, stream>>>(A, Bt, bias, (void*)out);
  }
}